// Round 8
// baseline (447.520 us; speedup 1.0000x reference)
//
#include <hip/hip_runtime.h>

// out[n, u*4+s] = sum_{e: dst[e]==n} x[src[e], u] * sh[e, s]
// N=100000, U=32, S=4, E=3200000.
//
// R5/R7 lesson: scatter into many (>~400) per-block write streams = 4.3x HBM
// write amp (166MB vs 38.4 ideal) — dirty-line working set exceeds per-XCD L2.
// R8: 3-level partition: 196 coarse buckets (runs of 64, amp~1.1) -> per-bucket
// split into 4 fine buckets (8 streams/block, ping-pong buffers) -> FUSED
// LDS-sort+register-accum per fine bucket (never writes sorted payload back).
// R2 kept: no bulk LDS float atomics. Tier-2 = proven R7 path (ws fallback).

#define U_DIM 32
#define US 128

// ---------- shared helpers ----------
__device__ inline unsigned f2bf(float f) {          // RNE float->bf16 bits
    unsigned u = __float_as_uint(f);
    return (u + 0x7FFF + ((u >> 16) & 1)) >> 16;
}
__device__ inline float bfl(unsigned w) { return __uint_as_float(w << 16); }
__device__ inline float bfh(unsigned w) { return __uint_as_float(w & 0xFFFF0000u); }

// x (f32) -> bf16 bits, vectorized.
__global__ void __launch_bounds__(256) xcvt_kernel(
        const float4* __restrict__ x4, ushort4* __restrict__ xb4, int n4) {
    int i = blockIdx.x * 256 + threadIdx.x;
    if (i < n4) {
        float4 v = x4[i];
        ushort4 r;
        r.x = (unsigned short)f2bf(v.x);
        r.y = (unsigned short)f2bf(v.y);
        r.z = (unsigned short)f2bf(v.z);
        r.w = (unsigned short)f2bf(v.w);
        xb4[i] = r;
    }
}

// =================== PRIMARY (3-level) PATH ===================
#define C1_LOG 9
#define C1_NPB 512            // nodes per coarse bucket
#define C1_MAXK 256
#define C1_NBLK 256           // stage-1 chunks
#define FINE_LOG 7
#define FINE_NPB 128          // nodes per fine bucket
#define FCAP 4608             // LDS-staged edges per fine-bucket chunk

__global__ void __launch_bounds__(1024) c1_hist_kernel(
        const int* __restrict__ dst, int* __restrict__ ccount,
        int* __restrict__ cnt, int E, int K1, int EPB) {
    __shared__ int h[C1_MAXK];
    for (int b = threadIdx.x; b < K1; b += 1024) h[b] = 0;
    __syncthreads();
    int base = blockIdx.x * EPB;
    int lim = min(EPB, E - base);
    for (int i = threadIdx.x; i < lim; i += 1024)
        atomicAdd(&h[dst[base + i] >> C1_LOG], 1);
    __syncthreads();
    for (int b = threadIdx.x; b < K1; b += 1024) {
        int c = h[b];
        cnt[b * C1_NBLK + blockIdx.x] = c;
        if (c) atomicAdd(&ccount[b], c);
    }
}

__global__ void __launch_bounds__(1024) c1_scan_kernel(
        const int* __restrict__ ccount, int* __restrict__ cbase,
        int* __restrict__ fbase, int K1, int E) {
    __shared__ int sc[1024];
    int t = threadIdx.x;
    int v = (t < K1) ? ccount[t] : 0;
    sc[t] = v;
    __syncthreads();
    for (int off = 1; off < 1024; off <<= 1) {
        int w = (t >= off) ? sc[t - off] : 0;
        __syncthreads();
        sc[t] += w;
        __syncthreads();
    }
    if (t < K1) cbase[t] = sc[t] - v;
    if (t == 0) { cbase[K1] = E; fbase[4 * K1] = E; }
}

__global__ void __launch_bounds__(C1_NBLK) c1_cbase_kernel(
        const int* __restrict__ cnt, const int* __restrict__ cbase,
        int* __restrict__ base_tab) {
    __shared__ int sc[C1_NBLK];
    int b = blockIdx.x;
    int t = threadIdx.x;
    int v = cnt[b * C1_NBLK + t];
    sc[t] = v;
    __syncthreads();
    for (int off = 1; off < C1_NBLK; off <<= 1) {
        int w = (t >= off) ? sc[t - off] : 0;
        __syncthreads();
        sc[t] += w;
        __syncthreads();
    }
    base_tab[b * C1_NBLK + t] = cbase[b] + sc[t] - v;
}

__global__ void __launch_bounds__(1024) c1_scatter_kernel(
        const int* __restrict__ dst, const int* __restrict__ src,
        const float4* __restrict__ sh, const int* __restrict__ base_tab,
        uint2* __restrict__ pay8A, int* __restrict__ packedA,
        int E, int K1, int EPB) {
    __shared__ int cur[C1_MAXK];
    for (int b = threadIdx.x; b < K1; b += 1024)
        cur[b] = base_tab[b * C1_NBLK + blockIdx.x];
    __syncthreads();
    int base = blockIdx.x * EPB;
    int lim = min(EPB, E - base);
    for (int i = threadIdx.x; i < lim; i += 1024) {
        int e = base + i;
        int d = dst[e];
        int b = d >> C1_LOG;
        int pos = atomicAdd(&cur[b], 1);
        float4 s4 = sh[e];
        pay8A[pos] = make_uint2(f2bf(s4.x) | (f2bf(s4.y) << 16),
                                f2bf(s4.z) | (f2bf(s4.w) << 16));
        packedA[pos] = ((d & (C1_NPB - 1)) << 21) | src[e];
    }
}

// One block per coarse bucket: split [cbeg,cend) into 4 fine sub-buckets
// (ping-pong A->B). Wave-aggregated cursor atomics; 8 write streams/block.
__global__ void __launch_bounds__(1024) c2_scatter_kernel(
        const int* __restrict__ cbase, const uint2* __restrict__ pay8A,
        const int* __restrict__ packedA, uint2* __restrict__ pay8B,
        int* __restrict__ packedB, int* __restrict__ fbase) {
    __shared__ int hist2[16 * 8];
    __shared__ int cur4[4];
    int b = blockIdx.x;
    int t = threadIdx.x;
    int wid = t >> 6, lane = t & 63;
    int cbeg = cbase[b], cend = cbase[b + 1];
    int cnt = cend - cbeg;
    if (t < 16 * 8) hist2[t] = 0;
    __syncthreads();
    for (int i = t; i < cnt; i += 1024) {
        int sub = (packedA[cbeg + i] >> 28) & 3;
        atomicAdd(&hist2[wid * 8 + sub], 1);
    }
    __syncthreads();
    if (t == 0) {
        int run = cbeg;
        for (int k = 0; k < 4; ++k) {
            int tot = 0;
            for (int w = 0; w < 16; ++w) tot += hist2[w * 8 + k];
            fbase[b * 4 + k] = run;
            cur4[k] = run;
            run += tot;
        }
    }
    __syncthreads();
    for (int i = t; i < cnt; i += 1024) {
        int pk = packedA[cbeg + i];
        uint2 p8 = pay8A[cbeg + i];
        int sub = (pk >> 28) & 3;
        int pos = 0;
        #pragma unroll
        for (int k = 0; k < 4; ++k) {
            unsigned long long m = __ballot(sub == k);
            if (m) {
                int leader = __ffsll((long long)m) - 1;
                int base_ = 0;
                if (lane == leader) base_ = atomicAdd(&cur4[k], __popcll(m));
                base_ = __shfl(base_, leader);
                if (sub == k)
                    pos = base_ + __popcll(m & ((1ull << lane) - 1ull));
            }
        }
        packedB[pos] = pk;
        pay8B[pos] = p8;
    }
}

// One block per fine bucket (128 nodes), 512 threads: LDS counting sort of
// each <=FCAP chunk, then register accumulation (wave w owns nodes w,w+8,..;
// lane: u=l&31, g=l>>5; acc[16][4] persists across chunks).
__global__ void __launch_bounds__(512) f_accum_kernel(
        const unsigned short* __restrict__ xb, const uint2* __restrict__ pay8B,
        const int* __restrict__ packedB, const int* __restrict__ fbase,
        float* __restrict__ out, int N) {
    __shared__ uint2 spay[FCAP];          // 36.9 KB
    __shared__ int   spk[FCAP];           // 18.4 KB
    __shared__ int   hist[8 * 132];       // per-wave hist, padded rows
    __shared__ int   soff[FINE_NPB + 1];
    __shared__ int   scur[FINE_NPB];
    __shared__ int   stmp[FINE_NPB];

    int fb = blockIdx.x;
    int t = threadIdx.x;
    int wid = t >> 6, lane = t & 63;
    int u = lane & 31, g = lane >> 5;
    int fbeg = fbase[fb], fend = fbase[fb + 1];
    int cnt = fend - fbeg;

    float4 acc[16];
    #pragma unroll
    for (int nn = 0; nn < 16; ++nn) acc[nn] = make_float4(0.f, 0.f, 0.f, 0.f);

    for (int cb = 0; cb < cnt; cb += FCAP) {
        int clen = min(FCAP, cnt - cb);
        for (int j = t; j < 8 * 132; j += 512) hist[j] = 0;
        __syncthreads();
        for (int i = t; i < clen; i += 512) {
            int node = (packedB[fbeg + cb + i] >> 21) & (FINE_NPB - 1);
            atomicAdd(&hist[wid * 132 + node], 1);
        }
        __syncthreads();
        if (t < FINE_NPB) {
            int tot = 0;
            #pragma unroll
            for (int w = 0; w < 8; ++w) tot += hist[w * 132 + t];
            stmp[t] = tot;
        }
        __syncthreads();
        // Hillis-Steele inclusive scan over 128 (guarded)
        for (int off = 1; off < FINE_NPB; off <<= 1) {
            int v = 0;
            if (t < FINE_NPB && t >= off) v = stmp[t - off];
            __syncthreads();
            if (t < FINE_NPB) stmp[t] += v;
            __syncthreads();
        }
        if (t < FINE_NPB) {
            int incl = stmp[t];
            int tot = 0;
            #pragma unroll
            for (int w = 0; w < 8; ++w) tot += hist[w * 132 + t];
            int excl = incl - tot;
            soff[t] = excl;
            scur[t] = excl;
            if (t == FINE_NPB - 1) soff[FINE_NPB] = clen;
        }
        __syncthreads();
        for (int i = t; i < clen; i += 512) {
            int pk = packedB[fbeg + cb + i];
            uint2 p8 = pay8B[fbeg + cb + i];
            int node = (pk >> 21) & (FINE_NPB - 1);
            int pos = atomicAdd(&scur[node], 1);
            spk[pos] = pk;
            spay[pos] = p8;
        }
        __syncthreads();
        #pragma unroll
        for (int nn = 0; nn < 16; ++nn) {
            int node = nn * 8 + wid;
            int b_ = soff[node], e_ = soff[node + 1];
            for (int i = b_ + g; i < e_; i += 2) {
                int pk = spk[i];
                uint2 q = spay[i];
                float xv = bfl((unsigned)xb[(size_t)(pk & 0x1FFFFF) * U_DIM + u]);
                acc[nn].x += xv * bfl(q.x);
                acc[nn].y += xv * bfh(q.x);
                acc[nn].z += xv * bfl(q.y);
                acc[nn].w += xv * bfh(q.y);
            }
        }
        __syncthreads();
    }
    #pragma unroll
    for (int nn = 0; nn < 16; ++nn) {
        acc[nn].x += __shfl_xor(acc[nn].x, 32);
        acc[nn].y += __shfl_xor(acc[nn].y, 32);
        acc[nn].z += __shfl_xor(acc[nn].z, 32);
        acc[nn].w += __shfl_xor(acc[nn].w, 32);
    }
    if (g == 0) {
        int nbase = fb << FINE_LOG;
        #pragma unroll
        for (int nn = 0; nn < 16; ++nn) {
            int ng = nbase + nn * 8 + wid;
            if (ng < N)
                *reinterpret_cast<float4*>(&out[(size_t)ng * US + u * 4]) = acc[nn];
        }
    }
}

// =================== TIER-2: proven R7 path ===================
#define LOG_NPBK 7
#define NPBK 128
#define MAXK 1024
#define NBLK 256
#define CAP 5120
#define SPILL_E 1000000

__global__ void __launch_bounds__(1024) coarse_hist_kernel(
        const int* __restrict__ dst, int* __restrict__ ccount,
        int* __restrict__ cnt, int E, int K, int EPB) {
    __shared__ int h[MAXK];
    for (int b = threadIdx.x; b < K; b += 1024) h[b] = 0;
    __syncthreads();
    int base = blockIdx.x * EPB;
    int lim = min(EPB, E - base);
    for (int i = threadIdx.x; i < lim; i += 1024)
        atomicAdd(&h[dst[base + i] >> LOG_NPBK], 1);
    __syncthreads();
    for (int b = threadIdx.x; b < K; b += 1024) {
        int c = h[b];
        cnt[b * NBLK + blockIdx.x] = c;
        if (c) atomicAdd(&ccount[b], c);
    }
}

__global__ void __launch_bounds__(1024) coarse_scan_kernel(
        const int* __restrict__ ccount, int* __restrict__ cbase,
        int* __restrict__ offsets, int* __restrict__ spill_cursor,
        int K, int N, int E) {
    __shared__ int sc[1024];
    int t = threadIdx.x;
    int v = (t < K) ? ccount[t] : 0;
    sc[t] = v;
    __syncthreads();
    for (int off = 1; off < 1024; off <<= 1) {
        int w = (t >= off) ? sc[t - off] : 0;
        __syncthreads();
        sc[t] += w;
        __syncthreads();
    }
    if (t < K) cbase[t] = sc[t] - v;
    if (t == 0) { cbase[K] = E; offsets[N] = E; *spill_cursor = 0; }
}

__global__ void __launch_bounds__(NBLK) chunk_base_kernel(
        const int* __restrict__ cnt, const int* __restrict__ cbase,
        int* __restrict__ base_tab) {
    __shared__ int sc[NBLK];
    int b = blockIdx.x;
    int t = threadIdx.x;
    int v = cnt[b * NBLK + t];
    sc[t] = v;
    __syncthreads();
    for (int off = 1; off < NBLK; off <<= 1) {
        int w = (t >= off) ? sc[t - off] : 0;
        __syncthreads();
        sc[t] += w;
        __syncthreads();
    }
    base_tab[b * NBLK + t] = cbase[b] + sc[t] - v;
}

__global__ void __launch_bounds__(1024) coarse_scatter_kernel(
        const int* __restrict__ dst, const int* __restrict__ src,
        const float4* __restrict__ sh, const int* __restrict__ base_tab,
        uint2* __restrict__ pay8, int* __restrict__ packed,
        int E, int K, int EPB) {
    __shared__ int cur[MAXK];
    for (int b = threadIdx.x; b < K; b += 1024)
        cur[b] = base_tab[b * NBLK + blockIdx.x];
    __syncthreads();
    int base = blockIdx.x * EPB;
    int lim = min(EPB, E - base);
    for (int i = threadIdx.x; i < lim; i += 1024) {
        int e = base + i;
        int d = dst[e];
        int b = d >> LOG_NPBK;
        int pos = atomicAdd(&cur[b], 1);
        float4 s4 = sh[e];
        pay8[pos] = make_uint2(f2bf(s4.x) | (f2bf(s4.y) << 16),
                               f2bf(s4.z) | (f2bf(s4.w) << 16));
        packed[pos] = ((d & (NPBK - 1)) << 24) | src[e];
    }
}

__global__ void __launch_bounds__(512) fine_sort_kernel(
        const int* __restrict__ cbase, int* __restrict__ offsets,
        uint2* __restrict__ pay8, int* __restrict__ packed,
        uint2* __restrict__ spill_pay, int* __restrict__ spill_pk,
        int* __restrict__ spill_cursor, int N) {
    __shared__ uint2 spay[CAP];
    __shared__ int   spk[CAP];
    __shared__ int   cnt_[NPBK];
    __shared__ int   sc[NPBK];
    __shared__ int   sbase_s;
    int b = blockIdx.x;
    int t = threadIdx.x;
    int cbeg = cbase[b], cend = cbase[b + 1];
    int cnt = cend - cbeg;
    if (t == 0) sbase_s = (cnt > CAP) ? atomicAdd(spill_cursor, cnt - CAP) : 0;
    if (t < NPBK) cnt_[t] = 0;
    __syncthreads();
    for (int i = t; i < cnt; i += 512) {
        int pk = packed[cbeg + i];
        uint2 p8 = pay8[cbeg + i];
        atomicAdd(&cnt_[(pk >> 24) & (NPBK - 1)], 1);
        if (i < CAP) { spk[i] = pk; spay[i] = p8; }
        else {
            int sp = sbase_s + (i - CAP);
            if (sp < SPILL_E) { spill_pk[sp] = pk; spill_pay[sp] = p8; }
        }
    }
    __syncthreads();
    int v = (t < NPBK) ? cnt_[t] : 0;
    if (t < NPBK) sc[t] = v;
    __syncthreads();
    for (int off = 1; off < NPBK; off <<= 1) {
        int w = (t < NPBK && t >= off) ? sc[t - off] : 0;
        __syncthreads();
        if (t < NPBK) sc[t] += w;
        __syncthreads();
    }
    if (t < NPBK) {
        int ex = sc[t] - v;
        int node = (b << LOG_NPBK) + t;
        if (node <= N) offsets[node] = cbeg + ex;
        cnt_[t] = ex;
    }
    __syncthreads();
    for (int i = t; i < cnt; i += 512) {
        int pk; uint2 p8;
        bool ok = true;
        if (i < CAP) { pk = spk[i]; p8 = spay[i]; }
        else {
            int sp = sbase_s + (i - CAP);
            ok = (sp < SPILL_E);
            if (ok) { pk = spill_pk[sp]; p8 = spill_pay[sp]; }
        }
        if (ok) {
            int pos = cbeg + atomicAdd(&cnt_[(pk >> 24) & (NPBK - 1)], 1);
            packed[pos] = pk;
            pay8[pos] = p8;
        }
    }
}

__global__ void __launch_bounds__(US) accum_kernel(
        const unsigned short* __restrict__ xb, const uint2* __restrict__ pay8,
        const int* __restrict__ packed, const int* __restrict__ offsets,
        float* __restrict__ out) {
    int n = blockIdx.x;
    int t = threadIdx.x;
    int u = t & 31;
    int g = t >> 5;
    int beg = offsets[n], end = offsets[n + 1];
    float a0 = 0.f, a1 = 0.f, a2 = 0.f, a3 = 0.f;
    int i = beg + g;
    for (; i < end; i += 4) {
        int pk = packed[i];
        uint2 q = pay8[i];
        float xv = bfl((unsigned)xb[(size_t)(pk & 0xFFFFFF) * U_DIM + u]);
        a0 += xv * bfl(q.x);
        a1 += xv * bfh(q.x);
        a2 += xv * bfl(q.y);
        a3 += xv * bfh(q.y);
    }
    a0 += __shfl_xor(a0, 32);
    a1 += __shfl_xor(a1, 32);
    a2 += __shfl_xor(a2, 32);
    a3 += __shfl_xor(a3, 32);
    __shared__ float red[US];
    int w = t >> 6, l = t & 63;
    if (w == 1 && l < 32) {
        red[l * 4 + 0] = a0; red[l * 4 + 1] = a1;
        red[l * 4 + 2] = a2; red[l * 4 + 3] = a3;
    }
    __syncthreads();
    if (w == 0 && l < 32) {
        float4 o = make_float4(a0 + red[l * 4 + 0], a1 + red[l * 4 + 1],
                               a2 + red[l * 4 + 2], a3 + red[l * 4 + 3]);
        *reinterpret_cast<float4*>(&out[(size_t)n * US + l * 4]) = o;
    }
}

// --- Fallback tier 3/4 ---
constexpr int SCAN_BLOCK = 256;
constexpr int SCAN_ITEMS = 8;
constexpr int SCAN_CHUNK = SCAN_BLOCK * SCAN_ITEMS;

__global__ void __launch_bounds__(256) hist_kernel(
        const int* __restrict__ dst, int* __restrict__ counts, int E) {
    int e = blockIdx.x * blockDim.x + threadIdx.x;
    if (e < E) atomicAdd(&counts[dst[e]], 1);
}
__global__ void __launch_bounds__(SCAN_BLOCK) block_sum_kernel(
        const int* __restrict__ counts, int* __restrict__ bsums, int N) {
    __shared__ int sdata[SCAN_BLOCK];
    int base = blockIdx.x * SCAN_CHUNK;
    int sum = 0;
    for (int j = 0; j < SCAN_ITEMS; ++j) {
        int idx = base + j * SCAN_BLOCK + threadIdx.x;
        if (idx < N) sum += counts[idx];
    }
    sdata[threadIdx.x] = sum;
    __syncthreads();
    for (int off = SCAN_BLOCK / 2; off > 0; off >>= 1) {
        if (threadIdx.x < off) sdata[threadIdx.x] += sdata[threadIdx.x + off];
        __syncthreads();
    }
    if (threadIdx.x == 0) bsums[blockIdx.x] = sdata[0];
}
__global__ void scan_bsums_kernel(int* __restrict__ bsums, int nb) {
    if (threadIdx.x == 0 && blockIdx.x == 0) {
        int acc = 0;
        for (int i = 0; i < nb; ++i) { int v = bsums[i]; bsums[i] = acc; acc += v; }
    }
}
__global__ void __launch_bounds__(SCAN_BLOCK) scan_final_kernel(
        const int* __restrict__ counts, const int* __restrict__ bsums,
        int* __restrict__ offsets, int* __restrict__ cursors, int N, int E) {
    __shared__ int sdata[SCAN_BLOCK];
    int base = blockIdx.x * SCAN_CHUNK + threadIdx.x * SCAN_ITEMS;
    int local[SCAN_ITEMS];
    int tsum = 0;
    for (int j = 0; j < SCAN_ITEMS; ++j) {
        int idx = base + j;
        int v = (idx < N) ? counts[idx] : 0;
        local[j] = tsum;
        tsum += v;
    }
    sdata[threadIdx.x] = tsum;
    __syncthreads();
    for (int off = 1; off < SCAN_BLOCK; off <<= 1) {
        int v = (threadIdx.x >= off) ? sdata[threadIdx.x - off] : 0;
        __syncthreads();
        sdata[threadIdx.x] += v;
        __syncthreads();
    }
    int excl = sdata[threadIdx.x] - tsum + bsums[blockIdx.x];
    for (int j = 0; j < SCAN_ITEMS; ++j) {
        int idx = base + j;
        if (idx < N) { int o = excl + local[j]; offsets[idx] = o; cursors[idx] = o; }
    }
    if (blockIdx.x == 0 && threadIdx.x == 0) offsets[N] = E;
}
__global__ void __launch_bounds__(256) scatter_ids_kernel(
        const int* __restrict__ dst, int* __restrict__ cursors,
        int* __restrict__ eids, int E) {
    int e = blockIdx.x * blockDim.x + threadIdx.x;
    if (e < E) { int pos = atomicAdd(&cursors[dst[e]], 1); eids[pos] = e; }
}
__global__ void __launch_bounds__(US) accum_ids_kernel(
        const float* __restrict__ x, const float* __restrict__ sh,
        const int* __restrict__ src, const int* __restrict__ offsets,
        const int* __restrict__ eids, float* __restrict__ out) {
    int n = blockIdx.x;
    int t = threadIdx.x;
    int u = t >> 2, s = t & 3;
    int beg = offsets[n], end = offsets[n + 1];
    float acc = 0.f;
    for (int i = beg; i < end; ++i) {
        int e = eids[i];
        acc += x[src[e] * U_DIM + u] * sh[e * 4 + s];
    }
    out[(size_t)n * US + t] = acc;
}
__global__ void __launch_bounds__(US) atomic_kernel(
        const float* __restrict__ x, const float* __restrict__ sh,
        const int* __restrict__ src, const int* __restrict__ dst,
        float* __restrict__ out, int E) {
    int e = blockIdx.x;
    int t = threadIdx.x;
    float v = x[src[e] * U_DIM + (t >> 2)] * sh[e * 4 + (t & 3)];
    atomicAdd(&out[(size_t)dst[e] * US + t], v);
}

extern "C" void kernel_launch(void* const* d_in, const int* in_sizes, int n_in,
                              void* d_out, int out_size, void* d_ws, size_t ws_size,
                              hipStream_t stream) {
    const float* x  = (const float*)d_in[0];
    const float* sh = (const float*)d_in[1];
    const int* src  = (const int*)d_in[2];
    const int* dst  = (const int*)d_in[3];
    float* out = (float*)d_out;

    const int E = in_sizes[2];
    const int N = in_sizes[0] / U_DIM;
    const int xn4 = in_sizes[0] / 4;
    const int egrid = (E + 255) / 256;
    const int nb = (N + SCAN_CHUNK - 1) / SCAN_CHUNK;

    // Primary (3-level): pay8A u2[E] | pay8B u2[E] | packedA i[E] | packedB i[E]
    //   | xb ushort[N*32] | ccount[K1] | cbase[K1+1] | cnt[K1*256] |
    //   base_tab[K1*256] | fbase[4*K1+1]
    const int K1 = (N + C1_NPB - 1) >> C1_LOG;
    const int EPB1 = (E + C1_NBLK - 1) / C1_NBLK;
    size_t need_main = (size_t)E * 24 + (size_t)in_sizes[0] * 2 +
                       (size_t)(2 * K1 + 2 + 2 * K1 * C1_NBLK + 4 * K1 + 1) * 4;

    // Tier-2 (R7): pay8 u2[E] | spill_pay u2[SPILL_E] | packed i[E] |
    //   spill_pk i[SPILL_E] | offsets[N+1] | ccount[K] | cbase[K+1] |
    //   cnt[K*256] | base_tab[K*256] | spill_cur | xb
    const int K = (N + NPBK - 1) >> LOG_NPBK;
    const int EPB = (E + NBLK - 1) / NBLK;
    size_t need_r7 = (size_t)E * 12 + (size_t)SPILL_E * 12 + (size_t)(N + 1) * 4 +
                     (size_t)(2 * K + 2) * 4 + (size_t)(2 * K * NBLK) * 4 +
                     (size_t)in_sizes[0] * 2;
    size_t need_ids = (size_t)E * 4 + (size_t)(3 * N + 1 + nb) * 4;

    if (K1 <= C1_MAXK && N <= (1 << 21) && (in_sizes[0] % 4 == 0) &&
        ws_size >= need_main) {
        uint2* pay8A   = (uint2*)d_ws;
        uint2* pay8B   = pay8A + E;
        int* packedA   = (int*)(pay8B + E);
        int* packedB   = packedA + E;
        unsigned short* xb = (unsigned short*)(packedB + E);
        int* ccount    = (int*)(xb + in_sizes[0]);
        int* cbase     = ccount + K1;
        int* cnt       = cbase + K1 + 1;
        int* base_tab  = cnt + K1 * C1_NBLK;
        int* fbase     = base_tab + K1 * C1_NBLK;

        hipMemsetAsync(ccount, 0, sizeof(int) * (size_t)K1, stream);
        xcvt_kernel<<<(xn4 + 255) / 256, 256, 0, stream>>>(
            (const float4*)x, (ushort4*)xb, xn4);
        c1_hist_kernel<<<C1_NBLK, 1024, 0, stream>>>(dst, ccount, cnt, E, K1, EPB1);
        c1_scan_kernel<<<1, 1024, 0, stream>>>(ccount, cbase, fbase, K1, E);
        c1_cbase_kernel<<<K1, C1_NBLK, 0, stream>>>(cnt, cbase, base_tab);
        c1_scatter_kernel<<<C1_NBLK, 1024, 0, stream>>>(dst, src, (const float4*)sh,
                                                        base_tab, pay8A, packedA,
                                                        E, K1, EPB1);
        c2_scatter_kernel<<<K1, 1024, 0, stream>>>(cbase, pay8A, packedA,
                                                   pay8B, packedB, fbase);
        f_accum_kernel<<<K1 * 4, 512, 0, stream>>>(xb, pay8B, packedB, fbase,
                                                   out, N);
    } else if (K <= MAXK && (in_sizes[0] % 4 == 0) && ws_size >= need_r7) {
        uint2* pay8      = (uint2*)d_ws;
        uint2* spill_pay = pay8 + E;
        int* packed      = (int*)(spill_pay + SPILL_E);
        int* spill_pk    = packed + E;
        int* offsets     = spill_pk + SPILL_E;
        int* ccount      = offsets + N + 1;
        int* cbase       = ccount + K;
        int* cnt         = cbase + K + 1;
        int* base_tab    = cnt + K * NBLK;
        int* spill_cur   = base_tab + K * NBLK;
        unsigned short* xb = (unsigned short*)(spill_cur + 1);

        hipMemsetAsync(ccount, 0, sizeof(int) * (size_t)K, stream);
        xcvt_kernel<<<(xn4 + 255) / 256, 256, 0, stream>>>(
            (const float4*)x, (ushort4*)xb, xn4);
        coarse_hist_kernel<<<NBLK, 1024, 0, stream>>>(dst, ccount, cnt, E, K, EPB);
        coarse_scan_kernel<<<1, 1024, 0, stream>>>(ccount, cbase, offsets,
                                                   spill_cur, K, N, E);
        chunk_base_kernel<<<K, NBLK, 0, stream>>>(cnt, cbase, base_tab);
        coarse_scatter_kernel<<<NBLK, 1024, 0, stream>>>(dst, src, (const float4*)sh,
                                                         base_tab, pay8, packed,
                                                         E, K, EPB);
        fine_sort_kernel<<<K, 512, 0, stream>>>(cbase, offsets, pay8, packed,
                                                spill_pay, spill_pk, spill_cur, N);
        accum_kernel<<<N, US, 0, stream>>>(xb, pay8, packed, offsets, out);
    } else if (ws_size >= need_ids) {
        int* eids    = (int*)d_ws;
        int* counts  = eids + E;
        int* offsets = counts + N;
        int* cursors = offsets + N + 1;
        int* bsums   = cursors + N;

        hipMemsetAsync(counts, 0, sizeof(int) * (size_t)N, stream);
        hist_kernel<<<egrid, 256, 0, stream>>>(dst, counts, E);
        block_sum_kernel<<<nb, SCAN_BLOCK, 0, stream>>>(counts, bsums, N);
        scan_bsums_kernel<<<1, 64, 0, stream>>>(bsums, nb);
        scan_final_kernel<<<nb, SCAN_BLOCK, 0, stream>>>(counts, bsums, offsets, cursors, N, E);
        scatter_ids_kernel<<<egrid, 256, 0, stream>>>(dst, cursors, eids, E);
        accum_ids_kernel<<<N, US, 0, stream>>>(x, sh, src, offsets, eids, out);
    } else {
        hipMemsetAsync(out, 0, sizeof(float) * (size_t)out_size, stream);
        atomic_kernel<<<E, US, 0, stream>>>(x, sh, src, dst, out, E);
    }
}

// Round 9
// 284.463 us; speedup vs baseline: 1.5732x; 1.5732x over previous
//
#include <hip/hip_runtime.h>

// out[n, u*4+s] = sum_{e: dst[e]==n} x[src[e], u] * sh[e, s]
// N=100000, U=32, S=4, E=3200000.
//
// R5/R7: >~400 write streams/block = 4.3x HBM write amp -> 3-level partition:
//   c1: 196 coarse buckets (runs of 64, amp~1.1), payload 12B (bf16x4 sh +
//       (dst&511)<<21|src), c2: per-bucket 4-way split (8 streams, ping-pong).
// R8 lesson: fused LDS-sort+accum = 784 deep-serial blocks, 17% occ, 357us.
//   One-block-per-node (100k shallow blocks) wins. So: fine_perm (light,
//   direct B->A permute, L2-local writes) + R7's per-node register accum.
// R2 kept: no bulk LDS float atomics.

#define U_DIM 32
#define US 128

__device__ inline unsigned f2bf(float f) {          // RNE float->bf16 bits
    unsigned u = __float_as_uint(f);
    return (u + 0x7FFF + ((u >> 16) & 1)) >> 16;
}
__device__ inline float bfl(unsigned w) { return __uint_as_float(w << 16); }
__device__ inline float bfh(unsigned w) { return __uint_as_float(w & 0xFFFF0000u); }

__global__ void __launch_bounds__(256) xcvt_kernel(
        const float4* __restrict__ x4, ushort4* __restrict__ xb4, int n4) {
    int i = blockIdx.x * 256 + threadIdx.x;
    if (i < n4) {
        float4 v = x4[i];
        ushort4 r;
        r.x = (unsigned short)f2bf(v.x);
        r.y = (unsigned short)f2bf(v.y);
        r.z = (unsigned short)f2bf(v.z);
        r.w = (unsigned short)f2bf(v.w);
        xb4[i] = r;
    }
}

// =================== PRIMARY (3-level) PATH ===================
#define C1_LOG 9
#define C1_NPB 512
#define C1_MAXK 256
#define C1_NBLK 256
#define FINE_LOG 7
#define FINE_NPB 128

__global__ void __launch_bounds__(1024) c1_hist_kernel(
        const int* __restrict__ dst, int* __restrict__ ccount,
        int* __restrict__ cnt, int E, int K1, int EPB) {
    __shared__ int h[C1_MAXK];
    for (int b = threadIdx.x; b < K1; b += 1024) h[b] = 0;
    __syncthreads();
    int base = blockIdx.x * EPB;
    int lim = min(EPB, E - base);
    for (int i = threadIdx.x; i < lim; i += 1024)
        atomicAdd(&h[dst[base + i] >> C1_LOG], 1);
    __syncthreads();
    for (int b = threadIdx.x; b < K1; b += 1024) {
        int c = h[b];
        cnt[b * C1_NBLK + blockIdx.x] = c;
        if (c) atomicAdd(&ccount[b], c);
    }
}

__global__ void __launch_bounds__(1024) c1_scan_kernel(
        const int* __restrict__ ccount, int* __restrict__ cbase,
        int* __restrict__ fbase, int* __restrict__ offsets,
        int K1, int N, int E) {
    __shared__ int sc[1024];
    int t = threadIdx.x;
    int v = (t < K1) ? ccount[t] : 0;
    sc[t] = v;
    __syncthreads();
    for (int off = 1; off < 1024; off <<= 1) {
        int w = (t >= off) ? sc[t - off] : 0;
        __syncthreads();
        sc[t] += w;
        __syncthreads();
    }
    if (t < K1) cbase[t] = sc[t] - v;
    if (t == 0) { cbase[K1] = E; fbase[4 * K1] = E; offsets[N] = E; }
}

__global__ void __launch_bounds__(C1_NBLK) c1_cbase_kernel(
        const int* __restrict__ cnt, const int* __restrict__ cbase,
        int* __restrict__ base_tab) {
    __shared__ int sc[C1_NBLK];
    int b = blockIdx.x;
    int t = threadIdx.x;
    int v = cnt[b * C1_NBLK + t];
    sc[t] = v;
    __syncthreads();
    for (int off = 1; off < C1_NBLK; off <<= 1) {
        int w = (t >= off) ? sc[t - off] : 0;
        __syncthreads();
        sc[t] += w;
        __syncthreads();
    }
    base_tab[b * C1_NBLK + t] = cbase[b] + sc[t] - v;
}

__global__ void __launch_bounds__(1024) c1_scatter_kernel(
        const int* __restrict__ dst, const int* __restrict__ src,
        const float4* __restrict__ sh, const int* __restrict__ base_tab,
        uint2* __restrict__ pay8A, int* __restrict__ packedA,
        int E, int K1, int EPB) {
    __shared__ int cur[C1_MAXK];
    for (int b = threadIdx.x; b < K1; b += 1024)
        cur[b] = base_tab[b * C1_NBLK + blockIdx.x];
    __syncthreads();
    int base = blockIdx.x * EPB;
    int lim = min(EPB, E - base);
    for (int i = threadIdx.x; i < lim; i += 1024) {
        int e = base + i;
        int d = dst[e];
        int b = d >> C1_LOG;
        int pos = atomicAdd(&cur[b], 1);
        float4 s4 = sh[e];
        pay8A[pos] = make_uint2(f2bf(s4.x) | (f2bf(s4.y) << 16),
                                f2bf(s4.z) | (f2bf(s4.w) << 16));
        packedA[pos] = ((d & (C1_NPB - 1)) << 21) | src[e];
    }
}

// One block per coarse bucket: split into 4 fine sub-buckets (A -> B).
__global__ void __launch_bounds__(1024) c2_scatter_kernel(
        const int* __restrict__ cbase, const uint2* __restrict__ pay8A,
        const int* __restrict__ packedA, uint2* __restrict__ pay8B,
        int* __restrict__ packedB, int* __restrict__ fbase) {
    __shared__ int hist2[16 * 8];
    __shared__ int cur4[4];
    int b = blockIdx.x;
    int t = threadIdx.x;
    int wid = t >> 6, lane = t & 63;
    int cbeg = cbase[b], cend = cbase[b + 1];
    int cnt = cend - cbeg;
    if (t < 16 * 8) hist2[t] = 0;
    __syncthreads();
    for (int i = t; i < cnt; i += 1024) {
        int sub = (packedA[cbeg + i] >> 28) & 3;
        atomicAdd(&hist2[wid * 8 + sub], 1);
    }
    __syncthreads();
    if (t == 0) {
        int run = cbeg;
        for (int k = 0; k < 4; ++k) {
            int tot = 0;
            for (int w = 0; w < 16; ++w) tot += hist2[w * 8 + k];
            fbase[b * 4 + k] = run;
            cur4[k] = run;
            run += tot;
        }
    }
    __syncthreads();
    for (int i = t; i < cnt; i += 1024) {
        int pk = packedA[cbeg + i];
        uint2 p8 = pay8A[cbeg + i];
        int sub = (pk >> 28) & 3;
        int pos = 0;
        #pragma unroll
        for (int k = 0; k < 4; ++k) {
            unsigned long long m = __ballot(sub == k);
            if (m) {
                int leader = __ffsll((long long)m) - 1;
                int base_ = 0;
                if (lane == leader) base_ = atomicAdd(&cur4[k], __popcll(m));
                base_ = __shfl(base_, leader);
                if (sub == k)
                    pos = base_ + __popcll(m & ((1ull << lane) - 1ull));
            }
        }
        packedB[pos] = pk;
        pay8B[pos] = p8;
    }
}

// One block per fine bucket (128 nodes): count -> scan (emits offsets[]) ->
// direct global B -> global A permute. Writes scatter only within the
// bucket's ~50KB window (L2-local). Light LDS -> high occupancy.
__global__ void __launch_bounds__(512) fine_perm_kernel(
        const int* __restrict__ fbase, int* __restrict__ offsets,
        const uint2* __restrict__ pay8B, const int* __restrict__ packedB,
        uint2* __restrict__ pay8A, int* __restrict__ packedA, int N) {
    __shared__ int scn[FINE_NPB];
    __shared__ int scur[FINE_NPB];
    int fb = blockIdx.x;
    int t = threadIdx.x;
    int fbeg = fbase[fb], fend = fbase[fb + 1];
    int cnt = fend - fbeg;
    if (t < FINE_NPB) scn[t] = 0;
    __syncthreads();
    for (int i = t; i < cnt; i += 512)
        atomicAdd(&scn[(packedB[fbeg + i] >> 21) & (FINE_NPB - 1)], 1);
    __syncthreads();
    int v = (t < FINE_NPB) ? scn[t] : 0;
    if (t < FINE_NPB) scur[t] = v;
    __syncthreads();
    for (int off = 1; off < FINE_NPB; off <<= 1) {
        int w = (t < FINE_NPB && t >= off) ? scur[t - off] : 0;
        __syncthreads();
        if (t < FINE_NPB) scur[t] += w;
        __syncthreads();
    }
    if (t < FINE_NPB) {
        int excl = scur[t] - v;
        int node = (fb << FINE_LOG) + t;
        if (node < N) offsets[node] = fbeg + excl;
        scur[t] = excl;
    }
    __syncthreads();
    for (int i = t; i < cnt; i += 512) {
        int pk = packedB[fbeg + i];
        uint2 p8 = pay8B[fbeg + i];
        int node = (pk >> 21) & (FINE_NPB - 1);
        int pos = fbeg + atomicAdd(&scur[node], 1);
        packedA[pos] = pk;
        pay8A[pos] = p8;
    }
}

// One block per node, 128 threads: u = t&31, edge-group g = t>>5 (stride 4).
__global__ void __launch_bounds__(US) accum_kernel(
        const unsigned short* __restrict__ xb, const uint2* __restrict__ pay8,
        const int* __restrict__ packed, const int* __restrict__ offsets,
        float* __restrict__ out, int smask) {
    int n = blockIdx.x;
    int t = threadIdx.x;
    int u = t & 31;
    int g = t >> 5;
    int beg = offsets[n], end = offsets[n + 1];
    float a0 = 0.f, a1 = 0.f, a2 = 0.f, a3 = 0.f;
    for (int i = beg + g; i < end; i += 4) {
        int pk = packed[i];
        uint2 q = pay8[i];
        float xv = bfl((unsigned)xb[(size_t)(pk & smask) * U_DIM + u]);
        a0 += xv * bfl(q.x);
        a1 += xv * bfh(q.x);
        a2 += xv * bfl(q.y);
        a3 += xv * bfh(q.y);
    }
    a0 += __shfl_xor(a0, 32);
    a1 += __shfl_xor(a1, 32);
    a2 += __shfl_xor(a2, 32);
    a3 += __shfl_xor(a3, 32);
    __shared__ float red[US];
    int w = t >> 6, l = t & 63;
    if (w == 1 && l < 32) {
        red[l * 4 + 0] = a0; red[l * 4 + 1] = a1;
        red[l * 4 + 2] = a2; red[l * 4 + 3] = a3;
    }
    __syncthreads();
    if (w == 0 && l < 32) {
        float4 o = make_float4(a0 + red[l * 4 + 0], a1 + red[l * 4 + 1],
                               a2 + red[l * 4 + 2], a3 + red[l * 4 + 3]);
        *reinterpret_cast<float4*>(&out[(size_t)n * US + l * 4]) = o;
    }
}

// =================== TIER-2: proven R7 path ===================
#define LOG_NPBK 7
#define NPBK 128
#define MAXK 1024
#define NBLK 256
#define CAP 5120
#define SPILL_E 1000000

__global__ void __launch_bounds__(1024) coarse_hist_kernel(
        const int* __restrict__ dst, int* __restrict__ ccount,
        int* __restrict__ cnt, int E, int K, int EPB) {
    __shared__ int h[MAXK];
    for (int b = threadIdx.x; b < K; b += 1024) h[b] = 0;
    __syncthreads();
    int base = blockIdx.x * EPB;
    int lim = min(EPB, E - base);
    for (int i = threadIdx.x; i < lim; i += 1024)
        atomicAdd(&h[dst[base + i] >> LOG_NPBK], 1);
    __syncthreads();
    for (int b = threadIdx.x; b < K; b += 1024) {
        int c = h[b];
        cnt[b * NBLK + blockIdx.x] = c;
        if (c) atomicAdd(&ccount[b], c);
    }
}

__global__ void __launch_bounds__(1024) coarse_scan_kernel(
        const int* __restrict__ ccount, int* __restrict__ cbase,
        int* __restrict__ offsets, int* __restrict__ spill_cursor,
        int K, int N, int E) {
    __shared__ int sc[1024];
    int t = threadIdx.x;
    int v = (t < K) ? ccount[t] : 0;
    sc[t] = v;
    __syncthreads();
    for (int off = 1; off < 1024; off <<= 1) {
        int w = (t >= off) ? sc[t - off] : 0;
        __syncthreads();
        sc[t] += w;
        __syncthreads();
    }
    if (t < K) cbase[t] = sc[t] - v;
    if (t == 0) { cbase[K] = E; offsets[N] = E; *spill_cursor = 0; }
}

__global__ void __launch_bounds__(NBLK) chunk_base_kernel(
        const int* __restrict__ cnt, const int* __restrict__ cbase,
        int* __restrict__ base_tab) {
    __shared__ int sc[NBLK];
    int b = blockIdx.x;
    int t = threadIdx.x;
    int v = cnt[b * NBLK + t];
    sc[t] = v;
    __syncthreads();
    for (int off = 1; off < NBLK; off <<= 1) {
        int w = (t >= off) ? sc[t - off] : 0;
        __syncthreads();
        sc[t] += w;
        __syncthreads();
    }
    base_tab[b * NBLK + t] = cbase[b] + sc[t] - v;
}

__global__ void __launch_bounds__(1024) coarse_scatter_kernel(
        const int* __restrict__ dst, const int* __restrict__ src,
        const float4* __restrict__ sh, const int* __restrict__ base_tab,
        uint2* __restrict__ pay8, int* __restrict__ packed,
        int E, int K, int EPB) {
    __shared__ int cur[MAXK];
    for (int b = threadIdx.x; b < K; b += 1024)
        cur[b] = base_tab[b * NBLK + blockIdx.x];
    __syncthreads();
    int base = blockIdx.x * EPB;
    int lim = min(EPB, E - base);
    for (int i = threadIdx.x; i < lim; i += 1024) {
        int e = base + i;
        int d = dst[e];
        int b = d >> LOG_NPBK;
        int pos = atomicAdd(&cur[b], 1);
        float4 s4 = sh[e];
        pay8[pos] = make_uint2(f2bf(s4.x) | (f2bf(s4.y) << 16),
                               f2bf(s4.z) | (f2bf(s4.w) << 16));
        packed[pos] = ((d & (NPBK - 1)) << 24) | src[e];
    }
}

__global__ void __launch_bounds__(512) fine_sort_kernel(
        const int* __restrict__ cbase, int* __restrict__ offsets,
        uint2* __restrict__ pay8, int* __restrict__ packed,
        uint2* __restrict__ spill_pay, int* __restrict__ spill_pk,
        int* __restrict__ spill_cursor, int N) {
    __shared__ uint2 spay[CAP];
    __shared__ int   spk[CAP];
    __shared__ int   cnt_[NPBK];
    __shared__ int   sc[NPBK];
    __shared__ int   sbase_s;
    int b = blockIdx.x;
    int t = threadIdx.x;
    int cbeg = cbase[b], cend = cbase[b + 1];
    int cnt = cend - cbeg;
    if (t == 0) sbase_s = (cnt > CAP) ? atomicAdd(spill_cursor, cnt - CAP) : 0;
    if (t < NPBK) cnt_[t] = 0;
    __syncthreads();
    for (int i = t; i < cnt; i += 512) {
        int pk = packed[cbeg + i];
        uint2 p8 = pay8[cbeg + i];
        atomicAdd(&cnt_[(pk >> 24) & (NPBK - 1)], 1);
        if (i < CAP) { spk[i] = pk; spay[i] = p8; }
        else {
            int sp = sbase_s + (i - CAP);
            if (sp < SPILL_E) { spill_pk[sp] = pk; spill_pay[sp] = p8; }
        }
    }
    __syncthreads();
    int v = (t < NPBK) ? cnt_[t] : 0;
    if (t < NPBK) sc[t] = v;
    __syncthreads();
    for (int off = 1; off < NPBK; off <<= 1) {
        int w = (t < NPBK && t >= off) ? sc[t - off] : 0;
        __syncthreads();
        if (t < NPBK) sc[t] += w;
        __syncthreads();
    }
    if (t < NPBK) {
        int ex = sc[t] - v;
        int node = (b << LOG_NPBK) + t;
        if (node <= N) offsets[node] = cbeg + ex;
        cnt_[t] = ex;
    }
    __syncthreads();
    for (int i = t; i < cnt; i += 512) {
        int pk; uint2 p8;
        bool ok = true;
        if (i < CAP) { pk = spk[i]; p8 = spay[i]; }
        else {
            int sp = sbase_s + (i - CAP);
            ok = (sp < SPILL_E);
            if (ok) { pk = spill_pk[sp]; p8 = spill_pay[sp]; }
        }
        if (ok) {
            int pos = cbeg + atomicAdd(&cnt_[(pk >> 24) & (NPBK - 1)], 1);
            packed[pos] = pk;
            pay8[pos] = p8;
        }
    }
}

// --- Fallback tiers 3/4 ---
constexpr int SCAN_BLOCK = 256;
constexpr int SCAN_ITEMS = 8;
constexpr int SCAN_CHUNK = SCAN_BLOCK * SCAN_ITEMS;

__global__ void __launch_bounds__(256) hist_kernel(
        const int* __restrict__ dst, int* __restrict__ counts, int E) {
    int e = blockIdx.x * blockDim.x + threadIdx.x;
    if (e < E) atomicAdd(&counts[dst[e]], 1);
}
__global__ void __launch_bounds__(SCAN_BLOCK) block_sum_kernel(
        const int* __restrict__ counts, int* __restrict__ bsums, int N) {
    __shared__ int sdata[SCAN_BLOCK];
    int base = blockIdx.x * SCAN_CHUNK;
    int sum = 0;
    for (int j = 0; j < SCAN_ITEMS; ++j) {
        int idx = base + j * SCAN_BLOCK + threadIdx.x;
        if (idx < N) sum += counts[idx];
    }
    sdata[threadIdx.x] = sum;
    __syncthreads();
    for (int off = SCAN_BLOCK / 2; off > 0; off >>= 1) {
        if (threadIdx.x < off) sdata[threadIdx.x] += sdata[threadIdx.x + off];
        __syncthreads();
    }
    if (threadIdx.x == 0) bsums[blockIdx.x] = sdata[0];
}
__global__ void scan_bsums_kernel(int* __restrict__ bsums, int nb) {
    if (threadIdx.x == 0 && blockIdx.x == 0) {
        int acc = 0;
        for (int i = 0; i < nb; ++i) { int v = bsums[i]; bsums[i] = acc; acc += v; }
    }
}
__global__ void __launch_bounds__(SCAN_BLOCK) scan_final_kernel(
        const int* __restrict__ counts, const int* __restrict__ bsums,
        int* __restrict__ offsets, int* __restrict__ cursors, int N, int E) {
    __shared__ int sdata[SCAN_BLOCK];
    int base = blockIdx.x * SCAN_CHUNK + threadIdx.x * SCAN_ITEMS;
    int local[SCAN_ITEMS];
    int tsum = 0;
    for (int j = 0; j < SCAN_ITEMS; ++j) {
        int idx = base + j;
        int v = (idx < N) ? counts[idx] : 0;
        local[j] = tsum;
        tsum += v;
    }
    sdata[threadIdx.x] = tsum;
    __syncthreads();
    for (int off = 1; off < SCAN_BLOCK; off <<= 1) {
        int v = (threadIdx.x >= off) ? sdata[threadIdx.x - off] : 0;
        __syncthreads();
        sdata[threadIdx.x] += v;
        __syncthreads();
    }
    int excl = sdata[threadIdx.x] - tsum + bsums[blockIdx.x];
    for (int j = 0; j < SCAN_ITEMS; ++j) {
        int idx = base + j;
        if (idx < N) { int o = excl + local[j]; offsets[idx] = o; cursors[idx] = o; }
    }
    if (blockIdx.x == 0 && threadIdx.x == 0) offsets[N] = E;
}
__global__ void __launch_bounds__(256) scatter_ids_kernel(
        const int* __restrict__ dst, int* __restrict__ cursors,
        int* __restrict__ eids, int E) {
    int e = blockIdx.x * blockDim.x + threadIdx.x;
    if (e < E) { int pos = atomicAdd(&cursors[dst[e]], 1); eids[pos] = e; }
}
__global__ void __launch_bounds__(US) accum_ids_kernel(
        const float* __restrict__ x, const float* __restrict__ sh,
        const int* __restrict__ src, const int* __restrict__ offsets,
        const int* __restrict__ eids, float* __restrict__ out) {
    int n = blockIdx.x;
    int t = threadIdx.x;
    int u = t >> 2, s = t & 3;
    int beg = offsets[n], end = offsets[n + 1];
    float acc = 0.f;
    for (int i = beg; i < end; ++i) {
        int e = eids[i];
        acc += x[src[e] * U_DIM + u] * sh[e * 4 + s];
    }
    out[(size_t)n * US + t] = acc;
}
__global__ void __launch_bounds__(US) atomic_kernel(
        const float* __restrict__ x, const float* __restrict__ sh,
        const int* __restrict__ src, const int* __restrict__ dst,
        float* __restrict__ out, int E) {
    int e = blockIdx.x;
    int t = threadIdx.x;
    float v = x[src[e] * U_DIM + (t >> 2)] * sh[e * 4 + (t & 3)];
    atomicAdd(&out[(size_t)dst[e] * US + t], v);
}

extern "C" void kernel_launch(void* const* d_in, const int* in_sizes, int n_in,
                              void* d_out, int out_size, void* d_ws, size_t ws_size,
                              hipStream_t stream) {
    const float* x  = (const float*)d_in[0];
    const float* sh = (const float*)d_in[1];
    const int* src  = (const int*)d_in[2];
    const int* dst  = (const int*)d_in[3];
    float* out = (float*)d_out;

    const int E = in_sizes[2];
    const int N = in_sizes[0] / U_DIM;
    const int xn4 = in_sizes[0] / 4;
    const int egrid = (E + 255) / 256;
    const int nb = (N + SCAN_CHUNK - 1) / SCAN_CHUNK;

    const int K1 = (N + C1_NPB - 1) >> C1_LOG;
    const int EPB1 = (E + C1_NBLK - 1) / C1_NBLK;
    // Primary: pay8A u2[E] | pay8B u2[E] | packedA i[E] | packedB i[E] |
    //   xb ushort[N*32] | offsets[N+1] | ccount[K1] | cbase[K1+1] |
    //   cnt[K1*256] | base_tab[K1*256] | fbase[4*K1+1]
    size_t need_main = (size_t)E * 24 + (size_t)in_sizes[0] * 2 +
                       (size_t)(N + 1 + 2 * K1 + 2 + 2 * K1 * C1_NBLK + 4 * K1 + 1) * 4;

    const int K = (N + NPBK - 1) >> LOG_NPBK;
    const int EPB = (E + NBLK - 1) / NBLK;
    size_t need_r7 = (size_t)E * 12 + (size_t)SPILL_E * 12 + (size_t)(N + 1) * 4 +
                     (size_t)(2 * K + 2) * 4 + (size_t)(2 * K * NBLK) * 4 +
                     (size_t)in_sizes[0] * 2;
    size_t need_ids = (size_t)E * 4 + (size_t)(3 * N + 1 + nb) * 4;

    if (K1 <= C1_MAXK && N <= (1 << 21) && (in_sizes[0] % 4 == 0) &&
        ws_size >= need_main) {
        uint2* pay8A   = (uint2*)d_ws;
        uint2* pay8B   = pay8A + E;
        int* packedA   = (int*)(pay8B + E);
        int* packedB   = packedA + E;
        unsigned short* xb = (unsigned short*)(packedB + E);
        int* offsets   = (int*)(xb + in_sizes[0]);
        int* ccount    = offsets + N + 1;
        int* cbase     = ccount + K1;
        int* cnt       = cbase + K1 + 1;
        int* base_tab  = cnt + K1 * C1_NBLK;
        int* fbase     = base_tab + K1 * C1_NBLK;

        hipMemsetAsync(ccount, 0, sizeof(int) * (size_t)K1, stream);
        xcvt_kernel<<<(xn4 + 255) / 256, 256, 0, stream>>>(
            (const float4*)x, (ushort4*)xb, xn4);
        c1_hist_kernel<<<C1_NBLK, 1024, 0, stream>>>(dst, ccount, cnt, E, K1, EPB1);
        c1_scan_kernel<<<1, 1024, 0, stream>>>(ccount, cbase, fbase, offsets,
                                               K1, N, E);
        c1_cbase_kernel<<<K1, C1_NBLK, 0, stream>>>(cnt, cbase, base_tab);
        c1_scatter_kernel<<<C1_NBLK, 1024, 0, stream>>>(dst, src, (const float4*)sh,
                                                        base_tab, pay8A, packedA,
                                                        E, K1, EPB1);
        c2_scatter_kernel<<<K1, 1024, 0, stream>>>(cbase, pay8A, packedA,
                                                   pay8B, packedB, fbase);
        fine_perm_kernel<<<K1 * 4, 512, 0, stream>>>(fbase, offsets, pay8B,
                                                     packedB, pay8A, packedA, N);
        accum_kernel<<<N, US, 0, stream>>>(xb, pay8A, packedA, offsets, out,
                                           0x1FFFFF);
    } else if (K <= MAXK && (in_sizes[0] % 4 == 0) && ws_size >= need_r7) {
        uint2* pay8      = (uint2*)d_ws;
        uint2* spill_pay = pay8 + E;
        int* packed      = (int*)(spill_pay + SPILL_E);
        int* spill_pk    = packed + E;
        int* offsets     = spill_pk + SPILL_E;
        int* ccount      = offsets + N + 1;
        int* cbase       = ccount + K;
        int* cnt         = cbase + K + 1;
        int* base_tab    = cnt + K * NBLK;
        int* spill_cur   = base_tab + K * NBLK;
        unsigned short* xb = (unsigned short*)(spill_cur + 1);

        hipMemsetAsync(ccount, 0, sizeof(int) * (size_t)K, stream);
        xcvt_kernel<<<(xn4 + 255) / 256, 256, 0, stream>>>(
            (const float4*)x, (ushort4*)xb, xn4);
        coarse_hist_kernel<<<NBLK, 1024, 0, stream>>>(dst, ccount, cnt, E, K, EPB);
        coarse_scan_kernel<<<1, 1024, 0, stream>>>(ccount, cbase, offsets,
                                                   spill_cur, K, N, E);
        chunk_base_kernel<<<K, NBLK, 0, stream>>>(cnt, cbase, base_tab);
        coarse_scatter_kernel<<<NBLK, 1024, 0, stream>>>(dst, src, (const float4*)sh,
                                                         base_tab, pay8, packed,
                                                         E, K, EPB);
        fine_sort_kernel<<<K, 512, 0, stream>>>(cbase, offsets, pay8, packed,
                                                spill_pay, spill_pk, spill_cur, N);
        accum_kernel<<<N, US, 0, stream>>>(xb, pay8, packed, offsets, out,
                                           0xFFFFFF);
    } else if (ws_size >= need_ids) {
        int* eids    = (int*)d_ws;
        int* counts  = eids + E;
        int* offsets = counts + N;
        int* cursors = offsets + N + 1;
        int* bsums   = cursors + N;

        hipMemsetAsync(counts, 0, sizeof(int) * (size_t)N, stream);
        hist_kernel<<<egrid, 256, 0, stream>>>(dst, counts, E);
        block_sum_kernel<<<nb, SCAN_BLOCK, 0, stream>>>(counts, bsums, N);
        scan_bsums_kernel<<<1, 64, 0, stream>>>(bsums, nb);
        scan_final_kernel<<<nb, SCAN_BLOCK, 0, stream>>>(counts, bsums, offsets, cursors, N, E);
        scatter_ids_kernel<<<egrid, 256, 0, stream>>>(dst, cursors, eids, E);
        accum_ids_kernel<<<N, US, 0, stream>>>(x, sh, src, offsets, eids, out);
    } else {
        hipMemsetAsync(out, 0, sizeof(float) * (size_t)out_size, stream);
        atomic_kernel<<<E, US, 0, stream>>>(x, sh, src, dst, out, E);
    }
}

// Round 10
// 283.046 us; speedup vs baseline: 1.5811x; 1.0050x over previous
//
#include <hip/hip_runtime.h>

// out[n, u*4+s] = sum_{e: dst[e]==n} x[src[e], u] * sh[e, s]
// N=100000, U=32, S=4, E=3200000.
//
// Ledger of lessons:
//  R2: bulk LDS float atomics = ~1 lane/cycle serial floor -> register accum.
//  R4/R5/R7: scattered writes into >~400 streams/block = 4.3x HBM write amp.
//  R8: few deep-serial blocks (17% occ) lose to 100k shallow blocks.
//  R9: accum FETCH 143MB = streams evicting the 6.4MB xb table from 4MB L2.
// R10: (a) NT loads for accum streams (protect xb in L2) + unroll-2;
//      (b) c2_sort = c2_scatter+fine_perm merged: filter parent range, LDS-
//          stage sorted, DENSE write-out (no scattered global writes at all).

#define U_DIM 32
#define US 128

__device__ inline unsigned f2bf(float f) {          // RNE float->bf16 bits
    unsigned u = __float_as_uint(f);
    return (u + 0x7FFF + ((u >> 16) & 1)) >> 16;
}
__device__ inline float bfl(unsigned w) { return __uint_as_float(w << 16); }
__device__ inline float bfh(unsigned w) { return __uint_as_float(w & 0xFFFF0000u); }

__global__ void __launch_bounds__(256) xcvt_kernel(
        const float4* __restrict__ x4, ushort4* __restrict__ xb4, int n4) {
    int i = blockIdx.x * 256 + threadIdx.x;
    if (i < n4) {
        float4 v = x4[i];
        ushort4 r;
        r.x = (unsigned short)f2bf(v.x);
        r.y = (unsigned short)f2bf(v.y);
        r.z = (unsigned short)f2bf(v.z);
        r.w = (unsigned short)f2bf(v.w);
        xb4[i] = r;
    }
}

// =================== PRIMARY PATH ===================
#define C1_LOG 9
#define C1_NPB 512
#define C1_MAXK 256
#define C1_NBLK 256
#define FINE_LOG 7
#define FINE_NPB 128
#define KF_MAX 1024
#define SCAP 5120             // LDS-staged edges per fine bucket (mean 4082)

// Fine-granularity (128-node) histogram; also per-chunk coarse counts.
__global__ void __launch_bounds__(1024) c1_hist_kernel(
        const int* __restrict__ dst, int* __restrict__ ccount_f,
        int* __restrict__ cnt, int E, int KF, int K1, int EPB) {
    __shared__ int h[KF_MAX];
    for (int b = threadIdx.x; b < KF; b += 1024) h[b] = 0;
    __syncthreads();
    int base = blockIdx.x * EPB;
    int lim = min(EPB, E - base);
    for (int i = threadIdx.x; i < lim; i += 1024)
        atomicAdd(&h[dst[base + i] >> FINE_LOG], 1);
    __syncthreads();
    for (int b = threadIdx.x; b < KF; b += 1024) {
        int c = h[b];
        if (c) atomicAdd(&ccount_f[b], c);
    }
    for (int b = threadIdx.x; b < K1; b += 1024) {
        int c = 0;
        #pragma unroll
        for (int k = 0; k < 4; ++k) {
            int f = 4 * b + k;
            if (f < KF) c += h[f];
        }
        cnt[b * C1_NBLK + blockIdx.x] = c;
    }
}

// One scan over KF fine counts -> fbase; cbase derived; offsets[N]=E.
__global__ void __launch_bounds__(1024) c1_scan_kernel(
        const int* __restrict__ ccount_f, int* __restrict__ fbase,
        int* __restrict__ cbase, int* __restrict__ offsets,
        int KF, int K1, int N, int E) {
    __shared__ int sc[1024];
    int t = threadIdx.x;
    int v = (t < KF) ? ccount_f[t] : 0;
    sc[t] = v;
    __syncthreads();
    for (int off = 1; off < 1024; off <<= 1) {
        int w = (t >= off) ? sc[t - off] : 0;
        __syncthreads();
        sc[t] += w;
        __syncthreads();
    }
    if (t < KF) fbase[t] = sc[t] - v;
    __syncthreads();
    if (t < K1) {
        int f = 4 * t;
        cbase[t] = (f < KF) ? (sc[f] - ccount_f[f]) : E;
    }
    if (t == 0) { fbase[KF] = E; cbase[K1] = E; offsets[N] = E; }
}

__global__ void __launch_bounds__(C1_NBLK) c1_cbase_kernel(
        const int* __restrict__ cnt, const int* __restrict__ cbase,
        int* __restrict__ base_tab) {
    __shared__ int sc[C1_NBLK];
    int b = blockIdx.x;
    int t = threadIdx.x;
    int v = cnt[b * C1_NBLK + t];
    sc[t] = v;
    __syncthreads();
    for (int off = 1; off < C1_NBLK; off <<= 1) {
        int w = (t >= off) ? sc[t - off] : 0;
        __syncthreads();
        sc[t] += w;
        __syncthreads();
    }
    base_tab[b * C1_NBLK + t] = cbase[b] + sc[t] - v;
}

__global__ void __launch_bounds__(1024) c1_scatter_kernel(
        const int* __restrict__ dst, const int* __restrict__ src,
        const float4* __restrict__ sh, const int* __restrict__ base_tab,
        uint2* __restrict__ pay8A, int* __restrict__ packedA,
        int E, int K1, int EPB) {
    __shared__ int cur[C1_MAXK];
    for (int b = threadIdx.x; b < K1; b += 1024)
        cur[b] = base_tab[b * C1_NBLK + blockIdx.x];
    __syncthreads();
    int base = blockIdx.x * EPB;
    int lim = min(EPB, E - base);
    for (int i = threadIdx.x; i < lim; i += 1024) {
        int e = base + i;
        int d = dst[e];
        int b = d >> C1_LOG;
        int pos = atomicAdd(&cur[b], 1);
        float4 s4 = sh[e];
        pay8A[pos] = make_uint2(f2bf(s4.x) | (f2bf(s4.y) << 16),
                                f2bf(s4.z) | (f2bf(s4.w) << 16));
        packedA[pos] = ((d & (C1_NPB - 1)) << 21) | src[e];
    }
}

// One block per fine bucket: stream parent coarse range (L2-shared with 3
// sibling blocks), filter own sub-bucket, LDS-stage in sorted order, then
// DENSE coalesced write-out to B. Emits offsets[]. No scattered global writes.
__global__ void __launch_bounds__(512) c2_sort_kernel(
        const int* __restrict__ cbase, const int* __restrict__ fbase,
        int* __restrict__ offsets, const uint2* __restrict__ pay8A,
        const int* __restrict__ packedA, uint2* __restrict__ pay8B,
        int* __restrict__ packedB, int N) {
    __shared__ uint2 spay[SCAP];          // 40 KB
    __shared__ int   spk[SCAP];           // 20 KB
    __shared__ int   hh[FINE_NPB];
    __shared__ int   scur[FINE_NPB];
    int fb = blockIdx.x;
    int t = threadIdx.x;
    int parent = fb >> 2, sub = fb & 3;
    int cbeg = cbase[parent], cend = cbase[parent + 1];
    int fbeg = fbase[fb];
    int cnt = fbase[fb + 1] - fbeg;
    if (t < FINE_NPB) hh[t] = 0;
    __syncthreads();
    for (int i = cbeg + t; i < cend; i += 512) {
        int nc = (packedA[i] >> 21) & (C1_NPB - 1);
        if ((nc >> FINE_LOG) == sub)
            atomicAdd(&hh[nc & (FINE_NPB - 1)], 1);
    }
    __syncthreads();
    int v = (t < FINE_NPB) ? hh[t] : 0;
    if (t < FINE_NPB) hh[t] = v;
    __syncthreads();
    for (int off = 1; off < FINE_NPB; off <<= 1) {
        int w = (t < FINE_NPB && t >= off) ? hh[t - off] : 0;
        __syncthreads();
        if (t < FINE_NPB) hh[t] += w;
        __syncthreads();
    }
    if (t < FINE_NPB) {
        int excl = hh[t] - v;
        scur[t] = excl;
        int node = (fb << FINE_LOG) + t;
        if (node < N) offsets[node] = fbeg + excl;
    }
    __syncthreads();
    for (int i = cbeg + t; i < cend; i += 512) {
        int pk = packedA[i];
        int nc = (pk >> 21) & (C1_NPB - 1);
        if ((nc >> FINE_LOG) == sub) {
            int pos = atomicAdd(&scur[nc & (FINE_NPB - 1)], 1);
            uint2 p8 = pay8A[i];
            if (pos < SCAP) { spk[pos] = pk; spay[pos] = p8; }
            else { packedB[fbeg + pos] = pk; pay8B[fbeg + pos] = p8; }
        }
    }
    __syncthreads();
    int lim = min(cnt, SCAP);
    for (int i = t; i < lim; i += 512) {
        packedB[fbeg + i] = spk[i];
        pay8B[fbeg + i] = spay[i];
    }
}

// One block per node, 128 threads: u = t&31, edge-group g = t>>5 (stride 4).
// NT loads on the one-pass streams keep xb resident in L2; unroll-2 for MLP.
__global__ void __launch_bounds__(US) accum_kernel(
        const unsigned short* __restrict__ xb, const uint2* __restrict__ pay8,
        const int* __restrict__ packed, const int* __restrict__ offsets,
        float* __restrict__ out, int smask) {
    int n = blockIdx.x;
    int t = threadIdx.x;
    int u = t & 31;
    int g = t >> 5;
    int beg = offsets[n], end = offsets[n + 1];
    float a0 = 0.f, a1 = 0.f, a2 = 0.f, a3 = 0.f;
    float b0 = 0.f, b1 = 0.f, b2 = 0.f, b3 = 0.f;
    int i = beg + g;
    for (; i + 4 < end; i += 8) {
        int pkA = __builtin_nontemporal_load(&packed[i]);
        int pkB = __builtin_nontemporal_load(&packed[i + 4]);
        unsigned long long qA =
            __builtin_nontemporal_load((const unsigned long long*)&pay8[i]);
        unsigned long long qB =
            __builtin_nontemporal_load((const unsigned long long*)&pay8[i + 4]);
        float xA = bfl((unsigned)xb[(size_t)(pkA & smask) * U_DIM + u]);
        float xB = bfl((unsigned)xb[(size_t)(pkB & smask) * U_DIM + u]);
        unsigned qAx = (unsigned)qA, qAy = (unsigned)(qA >> 32);
        unsigned qBx = (unsigned)qB, qBy = (unsigned)(qB >> 32);
        a0 += xA * bfl(qAx); a1 += xA * bfh(qAx);
        a2 += xA * bfl(qAy); a3 += xA * bfh(qAy);
        b0 += xB * bfl(qBx); b1 += xB * bfh(qBx);
        b2 += xB * bfl(qBy); b3 += xB * bfh(qBy);
    }
    if (i < end) {
        int pk = __builtin_nontemporal_load(&packed[i]);
        unsigned long long q =
            __builtin_nontemporal_load((const unsigned long long*)&pay8[i]);
        float xv = bfl((unsigned)xb[(size_t)(pk & smask) * U_DIM + u]);
        unsigned qx = (unsigned)q, qy = (unsigned)(q >> 32);
        a0 += xv * bfl(qx); a1 += xv * bfh(qx);
        a2 += xv * bfl(qy); a3 += xv * bfh(qy);
    }
    a0 += b0; a1 += b1; a2 += b2; a3 += b3;
    a0 += __shfl_xor(a0, 32);
    a1 += __shfl_xor(a1, 32);
    a2 += __shfl_xor(a2, 32);
    a3 += __shfl_xor(a3, 32);
    __shared__ float red[US];
    int w = t >> 6, l = t & 63;
    if (w == 1 && l < 32) {
        red[l * 4 + 0] = a0; red[l * 4 + 1] = a1;
        red[l * 4 + 2] = a2; red[l * 4 + 3] = a3;
    }
    __syncthreads();
    if (w == 0 && l < 32) {
        float4 o = make_float4(a0 + red[l * 4 + 0], a1 + red[l * 4 + 1],
                               a2 + red[l * 4 + 2], a3 + red[l * 4 + 3]);
        *reinterpret_cast<float4*>(&out[(size_t)n * US + l * 4]) = o;
    }
}

// =================== TIER-2: proven R7 path ===================
#define LOG_NPBK 7
#define NPBK 128
#define MAXK 1024
#define NBLK 256
#define CAP 5120
#define SPILL_E 1000000

__global__ void __launch_bounds__(1024) coarse_hist_kernel(
        const int* __restrict__ dst, int* __restrict__ ccount,
        int* __restrict__ cnt, int E, int K, int EPB) {
    __shared__ int h[MAXK];
    for (int b = threadIdx.x; b < K; b += 1024) h[b] = 0;
    __syncthreads();
    int base = blockIdx.x * EPB;
    int lim = min(EPB, E - base);
    for (int i = threadIdx.x; i < lim; i += 1024)
        atomicAdd(&h[dst[base + i] >> LOG_NPBK], 1);
    __syncthreads();
    for (int b = threadIdx.x; b < K; b += 1024) {
        int c = h[b];
        cnt[b * NBLK + blockIdx.x] = c;
        if (c) atomicAdd(&ccount[b], c);
    }
}

__global__ void __launch_bounds__(1024) coarse_scan_kernel(
        const int* __restrict__ ccount, int* __restrict__ cbase,
        int* __restrict__ offsets, int* __restrict__ spill_cursor,
        int K, int N, int E) {
    __shared__ int sc[1024];
    int t = threadIdx.x;
    int v = (t < K) ? ccount[t] : 0;
    sc[t] = v;
    __syncthreads();
    for (int off = 1; off < 1024; off <<= 1) {
        int w = (t >= off) ? sc[t - off] : 0;
        __syncthreads();
        sc[t] += w;
        __syncthreads();
    }
    if (t < K) cbase[t] = sc[t] - v;
    if (t == 0) { cbase[K] = E; offsets[N] = E; *spill_cursor = 0; }
}

__global__ void __launch_bounds__(NBLK) chunk_base_kernel(
        const int* __restrict__ cnt, const int* __restrict__ cbase,
        int* __restrict__ base_tab) {
    __shared__ int sc[NBLK];
    int b = blockIdx.x;
    int t = threadIdx.x;
    int v = cnt[b * NBLK + t];
    sc[t] = v;
    __syncthreads();
    for (int off = 1; off < NBLK; off <<= 1) {
        int w = (t >= off) ? sc[t - off] : 0;
        __syncthreads();
        sc[t] += w;
        __syncthreads();
    }
    base_tab[b * NBLK + t] = cbase[b] + sc[t] - v;
}

__global__ void __launch_bounds__(1024) coarse_scatter_kernel(
        const int* __restrict__ dst, const int* __restrict__ src,
        const float4* __restrict__ sh, const int* __restrict__ base_tab,
        uint2* __restrict__ pay8, int* __restrict__ packed,
        int E, int K, int EPB) {
    __shared__ int cur[MAXK];
    for (int b = threadIdx.x; b < K; b += 1024)
        cur[b] = base_tab[b * NBLK + blockIdx.x];
    __syncthreads();
    int base = blockIdx.x * EPB;
    int lim = min(EPB, E - base);
    for (int i = threadIdx.x; i < lim; i += 1024) {
        int e = base + i;
        int d = dst[e];
        int b = d >> LOG_NPBK;
        int pos = atomicAdd(&cur[b], 1);
        float4 s4 = sh[e];
        pay8[pos] = make_uint2(f2bf(s4.x) | (f2bf(s4.y) << 16),
                               f2bf(s4.z) | (f2bf(s4.w) << 16));
        packed[pos] = ((d & (NPBK - 1)) << 24) | src[e];
    }
}

__global__ void __launch_bounds__(512) fine_sort_kernel(
        const int* __restrict__ cbase, int* __restrict__ offsets,
        uint2* __restrict__ pay8, int* __restrict__ packed,
        uint2* __restrict__ spill_pay, int* __restrict__ spill_pk,
        int* __restrict__ spill_cursor, int N) {
    __shared__ uint2 spay[CAP];
    __shared__ int   spk[CAP];
    __shared__ int   cnt_[NPBK];
    __shared__ int   sc[NPBK];
    __shared__ int   sbase_s;
    int b = blockIdx.x;
    int t = threadIdx.x;
    int cbeg = cbase[b], cend = cbase[b + 1];
    int cnt = cend - cbeg;
    if (t == 0) sbase_s = (cnt > CAP) ? atomicAdd(spill_cursor, cnt - CAP) : 0;
    if (t < NPBK) cnt_[t] = 0;
    __syncthreads();
    for (int i = t; i < cnt; i += 512) {
        int pk = packed[cbeg + i];
        uint2 p8 = pay8[cbeg + i];
        atomicAdd(&cnt_[(pk >> 24) & (NPBK - 1)], 1);
        if (i < CAP) { spk[i] = pk; spay[i] = p8; }
        else {
            int sp = sbase_s + (i - CAP);
            if (sp < SPILL_E) { spill_pk[sp] = pk; spill_pay[sp] = p8; }
        }
    }
    __syncthreads();
    int v = (t < NPBK) ? cnt_[t] : 0;
    if (t < NPBK) sc[t] = v;
    __syncthreads();
    for (int off = 1; off < NPBK; off <<= 1) {
        int w = (t < NPBK && t >= off) ? sc[t - off] : 0;
        __syncthreads();
        if (t < NPBK) sc[t] += w;
        __syncthreads();
    }
    if (t < NPBK) {
        int ex = sc[t] - v;
        int node = (b << LOG_NPBK) + t;
        if (node <= N) offsets[node] = cbeg + ex;
        cnt_[t] = ex;
    }
    __syncthreads();
    for (int i = t; i < cnt; i += 512) {
        int pk; uint2 p8;
        bool ok = true;
        if (i < CAP) { pk = spk[i]; p8 = spay[i]; }
        else {
            int sp = sbase_s + (i - CAP);
            ok = (sp < SPILL_E);
            if (ok) { pk = spill_pk[sp]; p8 = spill_pay[sp]; }
        }
        if (ok) {
            int pos = cbeg + atomicAdd(&cnt_[(pk >> 24) & (NPBK - 1)], 1);
            packed[pos] = pk;
            pay8[pos] = p8;
        }
    }
}

// --- Fallback tiers 3/4 ---
constexpr int SCAN_BLOCK = 256;
constexpr int SCAN_ITEMS = 8;
constexpr int SCAN_CHUNK = SCAN_BLOCK * SCAN_ITEMS;

__global__ void __launch_bounds__(256) hist_kernel(
        const int* __restrict__ dst, int* __restrict__ counts, int E) {
    int e = blockIdx.x * blockDim.x + threadIdx.x;
    if (e < E) atomicAdd(&counts[dst[e]], 1);
}
__global__ void __launch_bounds__(SCAN_BLOCK) block_sum_kernel(
        const int* __restrict__ counts, int* __restrict__ bsums, int N) {
    __shared__ int sdata[SCAN_BLOCK];
    int base = blockIdx.x * SCAN_CHUNK;
    int sum = 0;
    for (int j = 0; j < SCAN_ITEMS; ++j) {
        int idx = base + j * SCAN_BLOCK + threadIdx.x;
        if (idx < N) sum += counts[idx];
    }
    sdata[threadIdx.x] = sum;
    __syncthreads();
    for (int off = SCAN_BLOCK / 2; off > 0; off >>= 1) {
        if (threadIdx.x < off) sdata[threadIdx.x] += sdata[threadIdx.x + off];
        __syncthreads();
    }
    if (threadIdx.x == 0) bsums[blockIdx.x] = sdata[0];
}
__global__ void scan_bsums_kernel(int* __restrict__ bsums, int nb) {
    if (threadIdx.x == 0 && blockIdx.x == 0) {
        int acc = 0;
        for (int i = 0; i < nb; ++i) { int v = bsums[i]; bsums[i] = acc; acc += v; }
    }
}
__global__ void __launch_bounds__(SCAN_BLOCK) scan_final_kernel(
        const int* __restrict__ counts, const int* __restrict__ bsums,
        int* __restrict__ offsets, int* __restrict__ cursors, int N, int E) {
    __shared__ int sdata[SCAN_BLOCK];
    int base = blockIdx.x * SCAN_CHUNK + threadIdx.x * SCAN_ITEMS;
    int local[SCAN_ITEMS];
    int tsum = 0;
    for (int j = 0; j < SCAN_ITEMS; ++j) {
        int idx = base + j;
        int v = (idx < N) ? counts[idx] : 0;
        local[j] = tsum;
        tsum += v;
    }
    sdata[threadIdx.x] = tsum;
    __syncthreads();
    for (int off = 1; off < SCAN_BLOCK; off <<= 1) {
        int v = (threadIdx.x >= off) ? sdata[threadIdx.x - off] : 0;
        __syncthreads();
        sdata[threadIdx.x] += v;
        __syncthreads();
    }
    int excl = sdata[threadIdx.x] - tsum + bsums[blockIdx.x];
    for (int j = 0; j < SCAN_ITEMS; ++j) {
        int idx = base + j;
        if (idx < N) { int o = excl + local[j]; offsets[idx] = o; cursors[idx] = o; }
    }
    if (blockIdx.x == 0 && threadIdx.x == 0) offsets[N] = E;
}
__global__ void __launch_bounds__(256) scatter_ids_kernel(
        const int* __restrict__ dst, int* __restrict__ cursors,
        int* __restrict__ eids, int E) {
    int e = blockIdx.x * blockDim.x + threadIdx.x;
    if (e < E) { int pos = atomicAdd(&cursors[dst[e]], 1); eids[pos] = e; }
}
__global__ void __launch_bounds__(US) accum_ids_kernel(
        const float* __restrict__ x, const float* __restrict__ sh,
        const int* __restrict__ src, const int* __restrict__ offsets,
        const int* __restrict__ eids, float* __restrict__ out) {
    int n = blockIdx.x;
    int t = threadIdx.x;
    int u = t >> 2, s = t & 3;
    int beg = offsets[n], end = offsets[n + 1];
    float acc = 0.f;
    for (int i = beg; i < end; ++i) {
        int e = eids[i];
        acc += x[src[e] * U_DIM + u] * sh[e * 4 + s];
    }
    out[(size_t)n * US + t] = acc;
}
__global__ void __launch_bounds__(US) atomic_kernel(
        const float* __restrict__ x, const float* __restrict__ sh,
        const int* __restrict__ src, const int* __restrict__ dst,
        float* __restrict__ out, int E) {
    int e = blockIdx.x;
    int t = threadIdx.x;
    float v = x[src[e] * U_DIM + (t >> 2)] * sh[e * 4 + (t & 3)];
    atomicAdd(&out[(size_t)dst[e] * US + t], v);
}

extern "C" void kernel_launch(void* const* d_in, const int* in_sizes, int n_in,
                              void* d_out, int out_size, void* d_ws, size_t ws_size,
                              hipStream_t stream) {
    const float* x  = (const float*)d_in[0];
    const float* sh = (const float*)d_in[1];
    const int* src  = (const int*)d_in[2];
    const int* dst  = (const int*)d_in[3];
    float* out = (float*)d_out;

    const int E = in_sizes[2];
    const int N = in_sizes[0] / U_DIM;
    const int xn4 = in_sizes[0] / 4;
    const int egrid = (E + 255) / 256;
    const int nb = (N + SCAN_CHUNK - 1) / SCAN_CHUNK;

    const int K1 = (N + C1_NPB - 1) >> C1_LOG;
    const int KF = (N + FINE_NPB - 1) >> FINE_LOG;
    const int EPB1 = (E + C1_NBLK - 1) / C1_NBLK;
    // Primary: pay8A u2[E] | pay8B u2[E] | packedA i[E] | packedB i[E] |
    //   xb ushort[N*32] | offsets[N+1] | ccount_f[KF] | fbase[KF+1] |
    //   cbase[K1+1] | cnt[K1*256] | base_tab[K1*256]
    size_t need_main = (size_t)E * 24 + (size_t)in_sizes[0] * 2 +
                       (size_t)(N + 1 + 2 * KF + 2 + K1 + 1 +
                                2 * K1 * C1_NBLK) * 4;

    const int K = (N + NPBK - 1) >> LOG_NPBK;
    const int EPB = (E + NBLK - 1) / NBLK;
    size_t need_r7 = (size_t)E * 12 + (size_t)SPILL_E * 12 + (size_t)(N + 1) * 4 +
                     (size_t)(2 * K + 2) * 4 + (size_t)(2 * K * NBLK) * 4 +
                     (size_t)in_sizes[0] * 2;
    size_t need_ids = (size_t)E * 4 + (size_t)(3 * N + 1 + nb) * 4;

    if (K1 <= C1_MAXK && KF <= KF_MAX && N <= (1 << 21) &&
        (in_sizes[0] % 4 == 0) && ws_size >= need_main) {
        uint2* pay8A   = (uint2*)d_ws;
        uint2* pay8B   = pay8A + E;
        int* packedA   = (int*)(pay8B + E);
        int* packedB   = packedA + E;
        unsigned short* xb = (unsigned short*)(packedB + E);
        int* offsets   = (int*)(xb + in_sizes[0]);
        int* ccount_f  = offsets + N + 1;
        int* fbase     = ccount_f + KF;
        int* cbase     = fbase + KF + 1;
        int* cnt       = cbase + K1 + 1;
        int* base_tab  = cnt + K1 * C1_NBLK;

        hipMemsetAsync(ccount_f, 0, sizeof(int) * (size_t)KF, stream);
        xcvt_kernel<<<(xn4 + 255) / 256, 256, 0, stream>>>(
            (const float4*)x, (ushort4*)xb, xn4);
        c1_hist_kernel<<<C1_NBLK, 1024, 0, stream>>>(dst, ccount_f, cnt,
                                                     E, KF, K1, EPB1);
        c1_scan_kernel<<<1, 1024, 0, stream>>>(ccount_f, fbase, cbase, offsets,
                                               KF, K1, N, E);
        c1_cbase_kernel<<<K1, C1_NBLK, 0, stream>>>(cnt, cbase, base_tab);
        c1_scatter_kernel<<<C1_NBLK, 1024, 0, stream>>>(dst, src, (const float4*)sh,
                                                        base_tab, pay8A, packedA,
                                                        E, K1, EPB1);
        c2_sort_kernel<<<KF, 512, 0, stream>>>(cbase, fbase, offsets,
                                               pay8A, packedA, pay8B, packedB, N);
        accum_kernel<<<N, US, 0, stream>>>(xb, pay8B, packedB, offsets, out,
                                           0x1FFFFF);
    } else if (K <= MAXK && (in_sizes[0] % 4 == 0) && ws_size >= need_r7) {
        uint2* pay8      = (uint2*)d_ws;
        uint2* spill_pay = pay8 + E;
        int* packed      = (int*)(spill_pay + SPILL_E);
        int* spill_pk    = packed + E;
        int* offsets     = spill_pk + SPILL_E;
        int* ccount      = offsets + N + 1;
        int* cbase       = ccount + K;
        int* cnt         = cbase + K + 1;
        int* base_tab    = cnt + K * NBLK;
        int* spill_cur   = base_tab + K * NBLK;
        unsigned short* xb = (unsigned short*)(spill_cur + 1);

        hipMemsetAsync(ccount, 0, sizeof(int) * (size_t)K, stream);
        xcvt_kernel<<<(xn4 + 255) / 256, 256, 0, stream>>>(
            (const float4*)x, (ushort4*)xb, xn4);
        coarse_hist_kernel<<<NBLK, 1024, 0, stream>>>(dst, ccount, cnt, E, K, EPB);
        coarse_scan_kernel<<<1, 1024, 0, stream>>>(ccount, cbase, offsets,
                                                   spill_cur, K, N, E);
        chunk_base_kernel<<<K, NBLK, 0, stream>>>(cnt, cbase, base_tab);
        coarse_scatter_kernel<<<NBLK, 1024, 0, stream>>>(dst, src, (const float4*)sh,
                                                         base_tab, pay8, packed,
                                                         E, K, EPB);
        fine_sort_kernel<<<K, 512, 0, stream>>>(cbase, offsets, pay8, packed,
                                                spill_pay, spill_pk, spill_cur, N);
        accum_kernel<<<N, US, 0, stream>>>(xb, pay8, packed, offsets, out,
                                           0xFFFFFF);
    } else if (ws_size >= need_ids) {
        int* eids    = (int*)d_ws;
        int* counts  = eids + E;
        int* offsets = counts + N;
        int* cursors = offsets + N + 1;
        int* bsums   = cursors + N;

        hipMemsetAsync(counts, 0, sizeof(int) * (size_t)N, stream);
        hist_kernel<<<egrid, 256, 0, stream>>>(dst, counts, E);
        block_sum_kernel<<<nb, SCAN_BLOCK, 0, stream>>>(counts, bsums, N);
        scan_bsums_kernel<<<1, 64, 0, stream>>>(bsums, nb);
        scan_final_kernel<<<nb, SCAN_BLOCK, 0, stream>>>(counts, bsums, offsets, cursors, N, E);
        scatter_ids_kernel<<<egrid, 256, 0, stream>>>(dst, cursors, eids, E);
        accum_ids_kernel<<<N, US, 0, stream>>>(x, sh, src, offsets, eids, out);
    } else {
        hipMemsetAsync(out, 0, sizeof(float) * (size_t)out_size, stream);
        atomic_kernel<<<E, US, 0, stream>>>(x, sh, src, dst, out, E);
    }
}

// Round 11
// 237.960 us; speedup vs baseline: 1.8807x; 1.1895x over previous
//
#include <hip/hip_runtime.h>

// out[n, u*4+s] = sum_{e: dst[e]==n} x[src[e], u] * sh[e, s]
// N=100000, U=32, S=4, E=3200000.
//
// Ledger of lessons:
//  R2: bulk LDS float atomics = ~1 lane/cycle serial floor -> register accum.
//  R4/R5/R7: scattered writes into >~400 streams/block = 4.3x HBM write amp.
//  R8: few deep-serial blocks (17% occ) lose to 100k shallow blocks.
//  R9: accum gather of 6.4MB xb is L3-served (xb > 4MB per-XCD L2, all XCDs
//      touch all rows) — structural; streams evicting L2 was secondary.
//  R10: NT loads on broadcast streams RE-FETCH shared lines (FETCH +11MB).
// R11: accum only — revert NT; g-lane owns a CONTIGUOUS quarter (mergeable
//      dwordx4 stream loads); unroll-4 => 4 independent xb gathers in flight.

#define U_DIM 32
#define US 128

__device__ inline unsigned f2bf(float f) {          // RNE float->bf16 bits
    unsigned u = __float_as_uint(f);
    return (u + 0x7FFF + ((u >> 16) & 1)) >> 16;
}
__device__ inline float bfl(unsigned w) { return __uint_as_float(w << 16); }
__device__ inline float bfh(unsigned w) { return __uint_as_float(w & 0xFFFF0000u); }

__global__ void __launch_bounds__(256) xcvt_kernel(
        const float4* __restrict__ x4, ushort4* __restrict__ xb4, int n4) {
    int i = blockIdx.x * 256 + threadIdx.x;
    if (i < n4) {
        float4 v = x4[i];
        ushort4 r;
        r.x = (unsigned short)f2bf(v.x);
        r.y = (unsigned short)f2bf(v.y);
        r.z = (unsigned short)f2bf(v.z);
        r.w = (unsigned short)f2bf(v.w);
        xb4[i] = r;
    }
}

// =================== PRIMARY PATH ===================
#define C1_LOG 9
#define C1_NPB 512
#define C1_MAXK 256
#define C1_NBLK 256
#define FINE_LOG 7
#define FINE_NPB 128
#define KF_MAX 1024
#define SCAP 5120             // LDS-staged edges per fine bucket (mean 4082)

// Fine-granularity (128-node) histogram; also per-chunk coarse counts.
__global__ void __launch_bounds__(1024) c1_hist_kernel(
        const int* __restrict__ dst, int* __restrict__ ccount_f,
        int* __restrict__ cnt, int E, int KF, int K1, int EPB) {
    __shared__ int h[KF_MAX];
    for (int b = threadIdx.x; b < KF; b += 1024) h[b] = 0;
    __syncthreads();
    int base = blockIdx.x * EPB;
    int lim = min(EPB, E - base);
    for (int i = threadIdx.x; i < lim; i += 1024)
        atomicAdd(&h[dst[base + i] >> FINE_LOG], 1);
    __syncthreads();
    for (int b = threadIdx.x; b < KF; b += 1024) {
        int c = h[b];
        if (c) atomicAdd(&ccount_f[b], c);
    }
    for (int b = threadIdx.x; b < K1; b += 1024) {
        int c = 0;
        #pragma unroll
        for (int k = 0; k < 4; ++k) {
            int f = 4 * b + k;
            if (f < KF) c += h[f];
        }
        cnt[b * C1_NBLK + blockIdx.x] = c;
    }
}

// One scan over KF fine counts -> fbase; cbase derived; offsets[N]=E.
__global__ void __launch_bounds__(1024) c1_scan_kernel(
        const int* __restrict__ ccount_f, int* __restrict__ fbase,
        int* __restrict__ cbase, int* __restrict__ offsets,
        int KF, int K1, int N, int E) {
    __shared__ int sc[1024];
    int t = threadIdx.x;
    int v = (t < KF) ? ccount_f[t] : 0;
    sc[t] = v;
    __syncthreads();
    for (int off = 1; off < 1024; off <<= 1) {
        int w = (t >= off) ? sc[t - off] : 0;
        __syncthreads();
        sc[t] += w;
        __syncthreads();
    }
    if (t < KF) fbase[t] = sc[t] - v;
    __syncthreads();
    if (t < K1) {
        int f = 4 * t;
        cbase[t] = (f < KF) ? (sc[f] - ccount_f[f]) : E;
    }
    if (t == 0) { fbase[KF] = E; cbase[K1] = E; offsets[N] = E; }
}

__global__ void __launch_bounds__(C1_NBLK) c1_cbase_kernel(
        const int* __restrict__ cnt, const int* __restrict__ cbase,
        int* __restrict__ base_tab) {
    __shared__ int sc[C1_NBLK];
    int b = blockIdx.x;
    int t = threadIdx.x;
    int v = cnt[b * C1_NBLK + t];
    sc[t] = v;
    __syncthreads();
    for (int off = 1; off < C1_NBLK; off <<= 1) {
        int w = (t >= off) ? sc[t - off] : 0;
        __syncthreads();
        sc[t] += w;
        __syncthreads();
    }
    base_tab[b * C1_NBLK + t] = cbase[b] + sc[t] - v;
}

__global__ void __launch_bounds__(1024) c1_scatter_kernel(
        const int* __restrict__ dst, const int* __restrict__ src,
        const float4* __restrict__ sh, const int* __restrict__ base_tab,
        uint2* __restrict__ pay8A, int* __restrict__ packedA,
        int E, int K1, int EPB) {
    __shared__ int cur[C1_MAXK];
    for (int b = threadIdx.x; b < K1; b += 1024)
        cur[b] = base_tab[b * C1_NBLK + blockIdx.x];
    __syncthreads();
    int base = blockIdx.x * EPB;
    int lim = min(EPB, E - base);
    for (int i = threadIdx.x; i < lim; i += 1024) {
        int e = base + i;
        int d = dst[e];
        int b = d >> C1_LOG;
        int pos = atomicAdd(&cur[b], 1);
        float4 s4 = sh[e];
        pay8A[pos] = make_uint2(f2bf(s4.x) | (f2bf(s4.y) << 16),
                                f2bf(s4.z) | (f2bf(s4.w) << 16));
        packedA[pos] = ((d & (C1_NPB - 1)) << 21) | src[e];
    }
}

// One block per fine bucket: stream parent coarse range (L2-shared with 3
// sibling blocks), filter own sub-bucket, LDS-stage in sorted order, then
// DENSE coalesced write-out to B. Emits offsets[]. No scattered global writes.
__global__ void __launch_bounds__(512) c2_sort_kernel(
        const int* __restrict__ cbase, const int* __restrict__ fbase,
        int* __restrict__ offsets, const uint2* __restrict__ pay8A,
        const int* __restrict__ packedA, uint2* __restrict__ pay8B,
        int* __restrict__ packedB, int N) {
    __shared__ uint2 spay[SCAP];          // 40 KB
    __shared__ int   spk[SCAP];           // 20 KB
    __shared__ int   hh[FINE_NPB];
    __shared__ int   scur[FINE_NPB];
    int fb = blockIdx.x;
    int t = threadIdx.x;
    int parent = fb >> 2, sub = fb & 3;
    int cbeg = cbase[parent], cend = cbase[parent + 1];
    int fbeg = fbase[fb];
    int cnt = fbase[fb + 1] - fbeg;
    if (t < FINE_NPB) hh[t] = 0;
    __syncthreads();
    for (int i = cbeg + t; i < cend; i += 512) {
        int nc = (packedA[i] >> 21) & (C1_NPB - 1);
        if ((nc >> FINE_LOG) == sub)
            atomicAdd(&hh[nc & (FINE_NPB - 1)], 1);
    }
    __syncthreads();
    int v = (t < FINE_NPB) ? hh[t] : 0;
    if (t < FINE_NPB) hh[t] = v;
    __syncthreads();
    for (int off = 1; off < FINE_NPB; off <<= 1) {
        int w = (t < FINE_NPB && t >= off) ? hh[t - off] : 0;
        __syncthreads();
        if (t < FINE_NPB) hh[t] += w;
        __syncthreads();
    }
    if (t < FINE_NPB) {
        int excl = hh[t] - v;
        scur[t] = excl;
        int node = (fb << FINE_LOG) + t;
        if (node < N) offsets[node] = fbeg + excl;
    }
    __syncthreads();
    for (int i = cbeg + t; i < cend; i += 512) {
        int pk = packedA[i];
        int nc = (pk >> 21) & (C1_NPB - 1);
        if ((nc >> FINE_LOG) == sub) {
            int pos = atomicAdd(&scur[nc & (FINE_NPB - 1)], 1);
            uint2 p8 = pay8A[i];
            if (pos < SCAP) { spk[pos] = pk; spay[pos] = p8; }
            else { packedB[fbeg + pos] = pk; pay8B[fbeg + pos] = p8; }
        }
    }
    __syncthreads();
    int lim = min(cnt, SCAP);
    for (int i = t; i < lim; i += 512) {
        packedB[fbeg + i] = spk[i];
        pay8B[fbeg + i] = spay[i];
    }
}

// One block per node, 128 threads: u = t&31, g = t>>5 owns a CONTIGUOUS
// quarter of the node's edges. Unroll-4: 4 independent xb gathers in flight;
// adjacent stream loads merge to dwordx4. No NT (R10 lesson).
__global__ void __launch_bounds__(US) accum_kernel(
        const unsigned short* __restrict__ xb, const uint2* __restrict__ pay8,
        const int* __restrict__ packed, const int* __restrict__ offsets,
        float* __restrict__ out, int smask) {
    int n = blockIdx.x;
    int t = threadIdx.x;
    int u = t & 31;
    int g = t >> 5;
    int beg = offsets[n], end = offsets[n + 1];
    int len = end - beg;
    int q0 = beg + ((len * g) >> 2);
    int q1 = beg + ((len * (g + 1)) >> 2);
    float a0 = 0.f, a1 = 0.f, a2 = 0.f, a3 = 0.f;
    int i = q0;
    for (; i + 3 < q1; i += 4) {
        int pk0 = packed[i], pk1 = packed[i + 1];
        int pk2 = packed[i + 2], pk3 = packed[i + 3];
        uint2 qv0 = pay8[i], qv1 = pay8[i + 1];
        uint2 qv2 = pay8[i + 2], qv3 = pay8[i + 3];
        float x0 = bfl((unsigned)xb[(size_t)(pk0 & smask) * U_DIM + u]);
        float x1 = bfl((unsigned)xb[(size_t)(pk1 & smask) * U_DIM + u]);
        float x2 = bfl((unsigned)xb[(size_t)(pk2 & smask) * U_DIM + u]);
        float x3 = bfl((unsigned)xb[(size_t)(pk3 & smask) * U_DIM + u]);
        a0 += x0 * bfl(qv0.x); a1 += x0 * bfh(qv0.x);
        a2 += x0 * bfl(qv0.y); a3 += x0 * bfh(qv0.y);
        a0 += x1 * bfl(qv1.x); a1 += x1 * bfh(qv1.x);
        a2 += x1 * bfl(qv1.y); a3 += x1 * bfh(qv1.y);
        a0 += x2 * bfl(qv2.x); a1 += x2 * bfh(qv2.x);
        a2 += x2 * bfl(qv2.y); a3 += x2 * bfh(qv2.y);
        a0 += x3 * bfl(qv3.x); a1 += x3 * bfh(qv3.x);
        a2 += x3 * bfl(qv3.y); a3 += x3 * bfh(qv3.y);
    }
    for (; i < q1; ++i) {
        int pk = packed[i];
        uint2 qv = pay8[i];
        float xv = bfl((unsigned)xb[(size_t)(pk & smask) * U_DIM + u]);
        a0 += xv * bfl(qv.x); a1 += xv * bfh(qv.x);
        a2 += xv * bfl(qv.y); a3 += xv * bfh(qv.y);
    }
    a0 += __shfl_xor(a0, 32);
    a1 += __shfl_xor(a1, 32);
    a2 += __shfl_xor(a2, 32);
    a3 += __shfl_xor(a3, 32);
    __shared__ float red[US];
    int w = t >> 6, l = t & 63;
    if (w == 1 && l < 32) {
        red[l * 4 + 0] = a0; red[l * 4 + 1] = a1;
        red[l * 4 + 2] = a2; red[l * 4 + 3] = a3;
    }
    __syncthreads();
    if (w == 0 && l < 32) {
        float4 o = make_float4(a0 + red[l * 4 + 0], a1 + red[l * 4 + 1],
                               a2 + red[l * 4 + 2], a3 + red[l * 4 + 3]);
        *reinterpret_cast<float4*>(&out[(size_t)n * US + l * 4]) = o;
    }
}

// =================== TIER-2: proven R7 path ===================
#define LOG_NPBK 7
#define NPBK 128
#define MAXK 1024
#define NBLK 256
#define CAP 5120
#define SPILL_E 1000000

__global__ void __launch_bounds__(1024) coarse_hist_kernel(
        const int* __restrict__ dst, int* __restrict__ ccount,
        int* __restrict__ cnt, int E, int K, int EPB) {
    __shared__ int h[MAXK];
    for (int b = threadIdx.x; b < K; b += 1024) h[b] = 0;
    __syncthreads();
    int base = blockIdx.x * EPB;
    int lim = min(EPB, E - base);
    for (int i = threadIdx.x; i < lim; i += 1024)
        atomicAdd(&h[dst[base + i] >> LOG_NPBK], 1);
    __syncthreads();
    for (int b = threadIdx.x; b < K; b += 1024) {
        int c = h[b];
        cnt[b * NBLK + blockIdx.x] = c;
        if (c) atomicAdd(&ccount[b], c);
    }
}

__global__ void __launch_bounds__(1024) coarse_scan_kernel(
        const int* __restrict__ ccount, int* __restrict__ cbase,
        int* __restrict__ offsets, int* __restrict__ spill_cursor,
        int K, int N, int E) {
    __shared__ int sc[1024];
    int t = threadIdx.x;
    int v = (t < K) ? ccount[t] : 0;
    sc[t] = v;
    __syncthreads();
    for (int off = 1; off < 1024; off <<= 1) {
        int w = (t >= off) ? sc[t - off] : 0;
        __syncthreads();
        sc[t] += w;
        __syncthreads();
    }
    if (t < K) cbase[t] = sc[t] - v;
    if (t == 0) { cbase[K] = E; offsets[N] = E; *spill_cursor = 0; }
}

__global__ void __launch_bounds__(NBLK) chunk_base_kernel(
        const int* __restrict__ cnt, const int* __restrict__ cbase,
        int* __restrict__ base_tab) {
    __shared__ int sc[NBLK];
    int b = blockIdx.x;
    int t = threadIdx.x;
    int v = cnt[b * NBLK + t];
    sc[t] = v;
    __syncthreads();
    for (int off = 1; off < NBLK; off <<= 1) {
        int w = (t >= off) ? sc[t - off] : 0;
        __syncthreads();
        sc[t] += w;
        __syncthreads();
    }
    base_tab[b * NBLK + t] = cbase[b] + sc[t] - v;
}

__global__ void __launch_bounds__(1024) coarse_scatter_kernel(
        const int* __restrict__ dst, const int* __restrict__ src,
        const float4* __restrict__ sh, const int* __restrict__ base_tab,
        uint2* __restrict__ pay8, int* __restrict__ packed,
        int E, int K, int EPB) {
    __shared__ int cur[MAXK];
    for (int b = threadIdx.x; b < K; b += 1024)
        cur[b] = base_tab[b * NBLK + blockIdx.x];
    __syncthreads();
    int base = blockIdx.x * EPB;
    int lim = min(EPB, E - base);
    for (int i = threadIdx.x; i < lim; i += 1024) {
        int e = base + i;
        int d = dst[e];
        int b = d >> LOG_NPBK;
        int pos = atomicAdd(&cur[b], 1);
        float4 s4 = sh[e];
        pay8[pos] = make_uint2(f2bf(s4.x) | (f2bf(s4.y) << 16),
                               f2bf(s4.z) | (f2bf(s4.w) << 16));
        packed[pos] = ((d & (NPBK - 1)) << 24) | src[e];
    }
}

__global__ void __launch_bounds__(512) fine_sort_kernel(
        const int* __restrict__ cbase, int* __restrict__ offsets,
        uint2* __restrict__ pay8, int* __restrict__ packed,
        uint2* __restrict__ spill_pay, int* __restrict__ spill_pk,
        int* __restrict__ spill_cursor, int N) {
    __shared__ uint2 spay[CAP];
    __shared__ int   spk[CAP];
    __shared__ int   cnt_[NPBK];
    __shared__ int   sc[NPBK];
    __shared__ int   sbase_s;
    int b = blockIdx.x;
    int t = threadIdx.x;
    int cbeg = cbase[b], cend = cbase[b + 1];
    int cnt = cend - cbeg;
    if (t == 0) sbase_s = (cnt > CAP) ? atomicAdd(spill_cursor, cnt - CAP) : 0;
    if (t < NPBK) cnt_[t] = 0;
    __syncthreads();
    for (int i = t; i < cnt; i += 512) {
        int pk = packed[cbeg + i];
        uint2 p8 = pay8[cbeg + i];
        atomicAdd(&cnt_[(pk >> 24) & (NPBK - 1)], 1);
        if (i < CAP) { spk[i] = pk; spay[i] = p8; }
        else {
            int sp = sbase_s + (i - CAP);
            if (sp < SPILL_E) { spill_pk[sp] = pk; spill_pay[sp] = p8; }
        }
    }
    __syncthreads();
    int v = (t < NPBK) ? cnt_[t] : 0;
    if (t < NPBK) sc[t] = v;
    __syncthreads();
    for (int off = 1; off < NPBK; off <<= 1) {
        int w = (t < NPBK && t >= off) ? sc[t - off] : 0;
        __syncthreads();
        if (t < NPBK) sc[t] += w;
        __syncthreads();
    }
    if (t < NPBK) {
        int ex = sc[t] - v;
        int node = (b << LOG_NPBK) + t;
        if (node <= N) offsets[node] = cbeg + ex;
        cnt_[t] = ex;
    }
    __syncthreads();
    for (int i = t; i < cnt; i += 512) {
        int pk; uint2 p8;
        bool ok = true;
        if (i < CAP) { pk = spk[i]; p8 = spay[i]; }
        else {
            int sp = sbase_s + (i - CAP);
            ok = (sp < SPILL_E);
            if (ok) { pk = spill_pk[sp]; p8 = spill_pay[sp]; }
        }
        if (ok) {
            int pos = cbeg + atomicAdd(&cnt_[(pk >> 24) & (NPBK - 1)], 1);
            packed[pos] = pk;
            pay8[pos] = p8;
        }
    }
}

// --- Fallback tiers 3/4 ---
constexpr int SCAN_BLOCK = 256;
constexpr int SCAN_ITEMS = 8;
constexpr int SCAN_CHUNK = SCAN_BLOCK * SCAN_ITEMS;

__global__ void __launch_bounds__(256) hist_kernel(
        const int* __restrict__ dst, int* __restrict__ counts, int E) {
    int e = blockIdx.x * blockDim.x + threadIdx.x;
    if (e < E) atomicAdd(&counts[dst[e]], 1);
}
__global__ void __launch_bounds__(SCAN_BLOCK) block_sum_kernel(
        const int* __restrict__ counts, int* __restrict__ bsums, int N) {
    __shared__ int sdata[SCAN_BLOCK];
    int base = blockIdx.x * SCAN_CHUNK;
    int sum = 0;
    for (int j = 0; j < SCAN_ITEMS; ++j) {
        int idx = base + j * SCAN_BLOCK + threadIdx.x;
        if (idx < N) sum += counts[idx];
    }
    sdata[threadIdx.x] = sum;
    __syncthreads();
    for (int off = SCAN_BLOCK / 2; off > 0; off >>= 1) {
        if (threadIdx.x < off) sdata[threadIdx.x] += sdata[threadIdx.x + off];
        __syncthreads();
    }
    if (threadIdx.x == 0) bsums[blockIdx.x] = sdata[0];
}
__global__ void scan_bsums_kernel(int* __restrict__ bsums, int nb) {
    if (threadIdx.x == 0 && blockIdx.x == 0) {
        int acc = 0;
        for (int i = 0; i < nb; ++i) { int v = bsums[i]; bsums[i] = acc; acc += v; }
    }
}
__global__ void __launch_bounds__(SCAN_BLOCK) scan_final_kernel(
        const int* __restrict__ counts, const int* __restrict__ bsums,
        int* __restrict__ offsets, int* __restrict__ cursors, int N, int E) {
    __shared__ int sdata[SCAN_BLOCK];
    int base = blockIdx.x * SCAN_CHUNK + threadIdx.x * SCAN_ITEMS;
    int local[SCAN_ITEMS];
    int tsum = 0;
    for (int j = 0; j < SCAN_ITEMS; ++j) {
        int idx = base + j;
        int v = (idx < N) ? counts[idx] : 0;
        local[j] = tsum;
        tsum += v;
    }
    sdata[threadIdx.x] = tsum;
    __syncthreads();
    for (int off = 1; off < SCAN_BLOCK; off <<= 1) {
        int v = (threadIdx.x >= off) ? sdata[threadIdx.x - off] : 0;
        __syncthreads();
        sdata[threadIdx.x] += v;
        __syncthreads();
    }
    int excl = sdata[threadIdx.x] - tsum + bsums[blockIdx.x];
    for (int j = 0; j < SCAN_ITEMS; ++j) {
        int idx = base + j;
        if (idx < N) { int o = excl + local[j]; offsets[idx] = o; cursors[idx] = o; }
    }
    if (blockIdx.x == 0 && threadIdx.x == 0) offsets[N] = E;
}
__global__ void __launch_bounds__(256) scatter_ids_kernel(
        const int* __restrict__ dst, int* __restrict__ cursors,
        int* __restrict__ eids, int E) {
    int e = blockIdx.x * blockDim.x + threadIdx.x;
    if (e < E) { int pos = atomicAdd(&cursors[dst[e]], 1); eids[pos] = e; }
}
__global__ void __launch_bounds__(US) accum_ids_kernel(
        const float* __restrict__ x, const float* __restrict__ sh,
        const int* __restrict__ src, const int* __restrict__ offsets,
        const int* __restrict__ eids, float* __restrict__ out) {
    int n = blockIdx.x;
    int t = threadIdx.x;
    int u = t >> 2, s = t & 3;
    int beg = offsets[n], end = offsets[n + 1];
    float acc = 0.f;
    for (int i = beg; i < end; ++i) {
        int e = eids[i];
        acc += x[src[e] * U_DIM + u] * sh[e * 4 + s];
    }
    out[(size_t)n * US + t] = acc;
}
__global__ void __launch_bounds__(US) atomic_kernel(
        const float* __restrict__ x, const float* __restrict__ sh,
        const int* __restrict__ src, const int* __restrict__ dst,
        float* __restrict__ out, int E) {
    int e = blockIdx.x;
    int t = threadIdx.x;
    float v = x[src[e] * U_DIM + (t >> 2)] * sh[e * 4 + (t & 3)];
    atomicAdd(&out[(size_t)dst[e] * US + t], v);
}

extern "C" void kernel_launch(void* const* d_in, const int* in_sizes, int n_in,
                              void* d_out, int out_size, void* d_ws, size_t ws_size,
                              hipStream_t stream) {
    const float* x  = (const float*)d_in[0];
    const float* sh = (const float*)d_in[1];
    const int* src  = (const int*)d_in[2];
    const int* dst  = (const int*)d_in[3];
    float* out = (float*)d_out;

    const int E = in_sizes[2];
    const int N = in_sizes[0] / U_DIM;
    const int xn4 = in_sizes[0] / 4;
    const int egrid = (E + 255) / 256;
    const int nb = (N + SCAN_CHUNK - 1) / SCAN_CHUNK;

    const int K1 = (N + C1_NPB - 1) >> C1_LOG;
    const int KF = (N + FINE_NPB - 1) >> FINE_LOG;
    const int EPB1 = (E + C1_NBLK - 1) / C1_NBLK;
    size_t need_main = (size_t)E * 24 + (size_t)in_sizes[0] * 2 +
                       (size_t)(N + 1 + 2 * KF + 2 + K1 + 1 +
                                2 * K1 * C1_NBLK) * 4;

    const int K = (N + NPBK - 1) >> LOG_NPBK;
    const int EPB = (E + NBLK - 1) / NBLK;
    size_t need_r7 = (size_t)E * 12 + (size_t)SPILL_E * 12 + (size_t)(N + 1) * 4 +
                     (size_t)(2 * K + 2) * 4 + (size_t)(2 * K * NBLK) * 4 +
                     (size_t)in_sizes[0] * 2;
    size_t need_ids = (size_t)E * 4 + (size_t)(3 * N + 1 + nb) * 4;

    if (K1 <= C1_MAXK && KF <= KF_MAX && N <= (1 << 21) &&
        (in_sizes[0] % 4 == 0) && ws_size >= need_main) {
        uint2* pay8A   = (uint2*)d_ws;
        uint2* pay8B   = pay8A + E;
        int* packedA   = (int*)(pay8B + E);
        int* packedB   = packedA + E;
        unsigned short* xb = (unsigned short*)(packedB + E);
        int* offsets   = (int*)(xb + in_sizes[0]);
        int* ccount_f  = offsets + N + 1;
        int* fbase     = ccount_f + KF;
        int* cbase     = fbase + KF + 1;
        int* cnt       = cbase + K1 + 1;
        int* base_tab  = cnt + K1 * C1_NBLK;

        hipMemsetAsync(ccount_f, 0, sizeof(int) * (size_t)KF, stream);
        xcvt_kernel<<<(xn4 + 255) / 256, 256, 0, stream>>>(
            (const float4*)x, (ushort4*)xb, xn4);
        c1_hist_kernel<<<C1_NBLK, 1024, 0, stream>>>(dst, ccount_f, cnt,
                                                     E, KF, K1, EPB1);
        c1_scan_kernel<<<1, 1024, 0, stream>>>(ccount_f, fbase, cbase, offsets,
                                               KF, K1, N, E);
        c1_cbase_kernel<<<K1, C1_NBLK, 0, stream>>>(cnt, cbase, base_tab);
        c1_scatter_kernel<<<C1_NBLK, 1024, 0, stream>>>(dst, src, (const float4*)sh,
                                                        base_tab, pay8A, packedA,
                                                        E, K1, EPB1);
        c2_sort_kernel<<<KF, 512, 0, stream>>>(cbase, fbase, offsets,
                                               pay8A, packedA, pay8B, packedB, N);
        accum_kernel<<<N, US, 0, stream>>>(xb, pay8B, packedB, offsets, out,
                                           0x1FFFFF);
    } else if (K <= MAXK && (in_sizes[0] % 4 == 0) && ws_size >= need_r7) {
        uint2* pay8      = (uint2*)d_ws;
        uint2* spill_pay = pay8 + E;
        int* packed      = (int*)(spill_pay + SPILL_E);
        int* spill_pk    = packed + E;
        int* offsets     = spill_pk + SPILL_E;
        int* ccount      = offsets + N + 1;
        int* cbase       = ccount + K;
        int* cnt         = cbase + K + 1;
        int* base_tab    = cnt + K * NBLK;
        int* spill_cur   = base_tab + K * NBLK;
        unsigned short* xb = (unsigned short*)(spill_cur + 1);

        hipMemsetAsync(ccount, 0, sizeof(int) * (size_t)K, stream);
        xcvt_kernel<<<(xn4 + 255) / 256, 256, 0, stream>>>(
            (const float4*)x, (ushort4*)xb, xn4);
        coarse_hist_kernel<<<NBLK, 1024, 0, stream>>>(dst, ccount, cnt, E, K, EPB);
        coarse_scan_kernel<<<1, 1024, 0, stream>>>(ccount, cbase, offsets,
                                                   spill_cur, K, N, E);
        chunk_base_kernel<<<K, NBLK, 0, stream>>>(cnt, cbase, base_tab);
        coarse_scatter_kernel<<<NBLK, 1024, 0, stream>>>(dst, src, (const float4*)sh,
                                                         base_tab, pay8, packed,
                                                         E, K, EPB);
        fine_sort_kernel<<<K, 512, 0, stream>>>(cbase, offsets, pay8, packed,
                                                spill_pay, spill_pk, spill_cur, N);
        accum_kernel<<<N, US, 0, stream>>>(xb, pay8, packed, offsets, out,
                                           0xFFFFFF);
    } else if (ws_size >= need_ids) {
        int* eids    = (int*)d_ws;
        int* counts  = eids + E;
        int* offsets = counts + N;
        int* cursors = offsets + N + 1;
        int* bsums   = cursors + N;

        hipMemsetAsync(counts, 0, sizeof(int) * (size_t)N, stream);
        hist_kernel<<<egrid, 256, 0, stream>>>(dst, counts, E);
        block_sum_kernel<<<nb, SCAN_BLOCK, 0, stream>>>(counts, bsums, N);
        scan_bsums_kernel<<<1, 64, 0, stream>>>(bsums, nb);
        scan_final_kernel<<<nb, SCAN_BLOCK, 0, stream>>>(counts, bsums, offsets, cursors, N, E);
        scatter_ids_kernel<<<egrid, 256, 0, stream>>>(dst, cursors, eids, E);
        accum_ids_kernel<<<N, US, 0, stream>>>(x, sh, src, offsets, eids, out);
    } else {
        hipMemsetAsync(out, 0, sizeof(float) * (size_t)out_size, stream);
        atomic_kernel<<<E, US, 0, stream>>>(x, sh, src, dst, out, E);
    }
}